// Round 3
// baseline (459.759 us; speedup 1.0000x reference)
//
#include <hip/hip_runtime.h>
#include <math.h>

#define DEV __device__ __forceinline__

// ---- MFMA fragment types (gfx950 16x16x32 bf16) ----
using frag_ab = __attribute__((ext_vector_type(8))) short;  // 8 bf16 (4 VGPRs)
using frag_cd = __attribute__((ext_vector_type(4))) float;  // 4 fp32

static constexpr float SCALE_C = 0.04419417382415922f;  // 512^-0.5

// ---- bf16 helpers (RNE) ----
DEV unsigned short f2bf(float f) {
    unsigned u = __float_as_uint(f);
    unsigned r = (u + 0x7FFFu + ((u >> 16) & 1u)) >> 16;
    return (unsigned short)r;
}
DEV float bf2f(unsigned short h) { return __uint_as_float(((unsigned)h) << 16); }

DEV void unpack8(uint4 q, float f[8]) {
    f[0] = bf2f((unsigned short)(q.x & 0xFFFFu)); f[1] = bf2f((unsigned short)(q.x >> 16));
    f[2] = bf2f((unsigned short)(q.y & 0xFFFFu)); f[3] = bf2f((unsigned short)(q.y >> 16));
    f[4] = bf2f((unsigned short)(q.z & 0xFFFFu)); f[5] = bf2f((unsigned short)(q.z >> 16));
    f[6] = bf2f((unsigned short)(q.w & 0xFFFFu)); f[7] = bf2f((unsigned short)(q.w >> 16));
}
DEV uint4 pack8(const float f[8]) {
    uint4 q;
    q.x = (unsigned)f2bf(f[0]) | ((unsigned)f2bf(f[1]) << 16);
    q.y = (unsigned)f2bf(f[2]) | ((unsigned)f2bf(f[3]) << 16);
    q.z = (unsigned)f2bf(f[4]) | ((unsigned)f2bf(f[5]) << 16);
    q.w = (unsigned)f2bf(f[6]) | ((unsigned)f2bf(f[7]) << 16);
    return q;
}

// ---- async global->LDS 16B (direct-to-LDS DMA; dest = wave base + lane*16) ----
DEV void gload_lds16(const void* g, void* l) {
    __builtin_amdgcn_global_load_lds(
        (const __attribute__((address_space(1))) void*)g,
        (__attribute__((address_space(3))) void*)l, 16, 0, 0);
}

// ---- elementwise converts ----
__global__ void k_conv_bf16(const float* __restrict__ s, unsigned short* __restrict__ d, int n) {
    int i = (blockIdx.x * 256 + threadIdx.x) * 4;
    if (i + 3 < n) {
        float4 v = *(const float4*)(s + i);
        ushort4 o;
        o.x = f2bf(v.x); o.y = f2bf(v.y); o.z = f2bf(v.z); o.w = f2bf(v.w);
        *(ushort4*)(d + i) = o;
    }
}

// src [K][N] f32 -> dst [N][K] bf16 (transposed weight for MFMA B-operand)
__global__ void k_transpose_bf16(const float* __restrict__ s, unsigned short* __restrict__ d, int K, int N) {
    int i = blockIdx.x * 256 + threadIdx.x;
    if (i >= K * N) return;
    int n = i / K, k = i - n * K;
    d[i] = f2bf(s[k * N + n]);
}

// ---- tile staging: 128 rows x 64 bf16 (16KB), XOR-swizzled layout (G4/rule 21):
// linear LDS dest (global_load_lds requirement) + inverse-swizzled per-lane
// global source; ds_read applies the same involution.
// 256 threads, 4 chunks of 4KB (32 rows each).
DEV void stage_async(const unsigned short* __restrict__ g, int ld, int k0, char* lds, int t) {
    const int sub = t >> 3;               // row within 32-row chunk
    const int b = (t & 7) << 4;           // physical byte col 0..112
    const int bs = b ^ ((sub & 7) << 4);  // swizzled source byte col
    const char* gb = (const char*)(g + k0) + (size_t)sub * (size_t)(ld * 2) + bs;
    char* lb = lds + ((t >> 6) << 10);    // wave-uniform LDS base
    const size_t rstep = (size_t)32 * (ld * 2);
#pragma unroll
    for (int r = 0; r < 4; ++r)
        gload_lds16(gb + r * rstep, lb + r * 4096);
}

// ---- one 128x128x64 MFMA step (2x2 waves, 4x4 frags each) ----
// bv streamed one fragment at a time to keep arch-VGPR pressure low
// (total budget at 3 waves/SIMD is 170 incl. 64 AGPR acc).
DEV void mfma_tile(const char* As, const char* Bs, int lane, int wr, int wc, frag_cd (&acc)[4][4]) {
#pragma unroll
    for (int ks = 0; ks < 2; ++ks) {
        const int boff = ks * 64 + ((lane >> 4) << 4);
        frag_ab av[4];
#pragma unroll
        for (int f = 0; f < 4; ++f) {
            int ra = wr * 64 + f * 16 + (lane & 15);
            av[f] = *(const frag_ab*)(As + ra * 128 + (boff ^ ((ra & 7) << 4)));
        }
#pragma unroll
        for (int j = 0; j < 4; ++j) {
            int rb = wc * 64 + j * 16 + (lane & 15);
            frag_ab bv = *(const frag_ab*)(Bs + rb * 128 + (boff ^ ((rb & 7) << 4)));
#pragma unroll
            for (int i = 0; i < 4; ++i)
                acc[i][j] = __builtin_amdgcn_mfma_f32_16x16x32_bf16(av[i], bv, acc[i][j], 0, 0, 0);
        }
    }
}

// ---- generic bf16 GEMM: C = act(A @ BT^T + bias); EPI: 0=store, 1=store+colsum, 2=colsum only ----
template <int ACT, int EPI>
__global__ __launch_bounds__(256, 3) void k_gemm(
    const unsigned short* __restrict__ A, const unsigned short* __restrict__ BT,
    const float* __restrict__ bias, unsigned short* __restrict__ out,
    float* __restrict__ colsum, int M, int N, int K) {
    __shared__ __align__(16) char As[16384];
    __shared__ __align__(16) char Bs[16384];
    __shared__ float colacc[128];
    const int t = threadIdx.x;
    const int lane = t & 63, wid = t >> 6, wr = wid >> 1, wc = wid & 1;
    const int m0 = blockIdx.x * 128, n0 = blockIdx.y * 128;
    if (EPI >= 1 && t < 128) colacc[t] = 0.f;
    frag_cd acc[4][4] = {};
    for (int k0 = 0; k0 < K; k0 += 64) {
        __syncthreads();
        stage_async(A + (size_t)m0 * K, K, k0, As, t);
        stage_async(BT + (size_t)n0 * K, K, k0, Bs, t);
        __syncthreads();
        mfma_tile(As, Bs, lane, wr, wc, acc);
    }
    // epilogue
    float bval[4];
#pragma unroll
    for (int j = 0; j < 4; ++j) bval[j] = bias[n0 + wc * 64 + j * 16 + (lane & 15)];
#pragma unroll
    for (int i = 0; i < 4; ++i) {
#pragma unroll
        for (int j = 0; j < 4; ++j) {
            float cs = 0.f;
#pragma unroll
            for (int r = 0; r < 4; ++r) {
                float v = acc[i][j][r] + bval[j];
                if (ACT) v = v > 0.f ? v : 0.01f * v;
                if (EPI != 2) {
                    int row = m0 + wr * 64 + i * 16 + (lane >> 4) * 4 + r;
                    int col = n0 + wc * 64 + j * 16 + (lane & 15);
                    out[(size_t)row * N + col] = f2bf(v);
                }
                cs += v;
            }
            if (EPI >= 1) atomicAdd(&colacc[wc * 64 + j * 16 + (lane & 15)], cs);
        }
    }
    if (EPI >= 1) {
        __syncthreads();
        if (t < 128) atomicAdd(&colsum[n0 + t], colacc[t]);
    }
}

// ---- x = 0.5*(x + colmean) in-place on bf16 ----
__global__ void k_update_x(unsigned short* __restrict__ xb, const float* __restrict__ colsum) {
    int i = (blockIdx.x * 256 + threadIdx.x) * 8;
    uint4 q = *(const uint4*)(xb + i);
    float f[8]; unpack8(q, f);
    int c0 = i & 511;
#pragma unroll
    for (int j = 0; j < 8; ++j) f[j] = 0.5f * (f[j] + colsum[c0 + j] * (1.f / 8192.f));
    *(uint4*)(xb + i) = pack8(f);
}

// ---- top-6 insertion (static-indexed, branchless shift) ----
DEV void topk6_insert(float (&v)[6], int (&ix)[6], float cv, int ci) {
    bool b[6];
#pragma unroll
    for (int j = 0; j < 6; ++j) b[j] = (cv > v[j]) || (cv == v[j] && ci < ix[j]);
    if (!b[5]) return;
#pragma unroll
    for (int j = 5; j >= 1; --j) {
        v[j] = b[j] ? (b[j - 1] ? v[j - 1] : cv) : v[j];
        ix[j] = b[j] ? (b[j - 1] ? ix[j - 1] : ci) : ix[j];
    }
    if (b[0]) { v[0] = cv; ix[0] = ci; }
}

// ---- fused attn-logit GEMM + partial top-6 ----
// grid (64 row-blocks, 16 col-splits); each block: 128 rows x 512 cols.
// LDS: As/Bs (32KB) unioned with the S spill tile (33.3KB) -> 3-4 blocks/CU.
__global__ __launch_bounds__(256, 3) void k_attn_topk(
    const unsigned short* __restrict__ ehb, const unsigned short* __restrict__ etb,
    float* __restrict__ pw, int* __restrict__ pi) {
    __shared__ __align__(16) char smem[33280];
    char* As = smem;
    char* Bs = smem + 16384;
    float* Stile = (float*)smem;  // 128 x 65 f32, live only between GEMM phases
    const int t = threadIdx.x;
    const int lane = t & 63, wid = t >> 6, wr = wid >> 1, wc = wid & 1;
    const int m0 = blockIdx.x * 128;
    const int csplit = blockIdx.y;
    const int srow = t >> 1, hh = t & 1;
    float tv[6]; int tix[6];
#pragma unroll
    for (int j = 0; j < 6; ++j) { tv[j] = -INFINITY; tix[j] = 0x7FFFFFFF; }

    for (int ct = 0; ct < 4; ++ct) {
        const int n0 = csplit * 512 + ct * 128;
        frag_cd acc[4][4] = {};
        for (int k0 = 0; k0 < 512; k0 += 64) {
            __syncthreads();  // protects prior Stile scan / prior tile reads
            stage_async(ehb + (size_t)m0 * 512, 512, k0, As, t);
            stage_async(etb + (size_t)n0 * 512, 512, k0, Bs, t);
            __syncthreads();  // compiler drains vmcnt(0) here (async loads done)
            mfma_tile(As, Bs, lane, wr, wc, acc);
        }
        // spill S-tile into (dead) As/Bs space in two 64-col chunks, scan top-6
#pragma unroll
        for (int ch = 0; ch < 2; ++ch) {
            __syncthreads();
            if (wc == ch) {
#pragma unroll
                for (int i = 0; i < 4; ++i)
#pragma unroll
                    for (int j = 0; j < 4; ++j)
#pragma unroll
                        for (int r = 0; r < 4; ++r) {
                            int row = wr * 64 + i * 16 + (lane >> 4) * 4 + r;
                            int col = j * 16 + (lane & 15);
                            Stile[row * 65 + col] = acc[i][j][r] * SCALE_C;
                        }
            }
            __syncthreads();
            const float* srowp = &Stile[srow * 65 + hh * 32];
            int gbase = n0 + ch * 64 + hh * 32;
            for (int s = 0; s < 32; ++s) {
                float cv = srowp[s];
                if (cv < tv[5]) continue;  // fast reject (ties handled by insert)
                topk6_insert(tv, tix, cv, gbase + s);
            }
        }
    }
    // merge the two half-row scanners via lane-pair shuffle (lanes 2k <-> 2k+1)
#pragma unroll
    for (int j = 0; j < 6; ++j) {
        float ov = __shfl_xor(tv[j], 1, 64);
        int oi = __shfl_xor(tix[j], 1, 64);
        if (hh == 0) topk6_insert(tv, tix, ov, oi);
    }
    if (hh == 0) {
        size_t o = ((size_t)(m0 + srow) * 16 + csplit) * 6;
#pragma unroll
        for (int j = 0; j < 6; ++j) { pw[o + j] = tv[j]; pi[o + j] = tix[j]; }
    }
}

// ---- merge 16 partial top-6 lists -> final top-6 per row ----
__global__ void k_merge_topk(const float* __restrict__ pw, const int* __restrict__ pi,
                             float* __restrict__ tw, int* __restrict__ ti) {
    int r = blockIdx.x * 256 + threadIdx.x;
    if (r >= 8192) return;
    float v[6]; int ix[6];
#pragma unroll
    for (int j = 0; j < 6; ++j) { v[j] = -INFINITY; ix[j] = 0x7FFFFFFF; }
    for (int s2 = 0; s2 < 16; ++s2) {
#pragma unroll
        for (int j = 0; j < 6; ++j) {
            size_t o = ((size_t)r * 16 + s2) * 6 + j;
            topk6_insert(v, ix, pw[o], pi[o]);
        }
    }
#pragma unroll
    for (int j = 0; j < 6; ++j) { tw[r * 6 + j] = v[j]; ti[r * 6 + j] = ix[j]; }
}

// ---- per-node neighbor aggregation: one wave per node ----
__global__ __launch_bounds__(256) void k_agg(
    const unsigned short* __restrict__ ehb, const unsigned short* __restrict__ etb,
    const float* __restrict__ tw, const int* __restrict__ ti,
    unsigned short* __restrict__ sb, unsigned short* __restrict__ pb) {
    const int t = threadIdx.x, lane = t & 63, wid = t >> 6;
    const int node = blockIdx.x * 4 + wid;
    const int d0 = lane * 8;
    float w[6]; int idx[6];
#pragma unroll
    for (int k = 0; k < 6; ++k) { w[k] = tw[node * 6 + k]; idx[k] = ti[node * 6 + k]; }
    float mx = w[0];
#pragma unroll
    for (int k = 1; k < 6; ++k) mx = fmaxf(mx, w[k]);
    float pr[6], s = 0.f;
#pragma unroll
    for (int k = 0; k < 6; ++k) { pr[k] = expf(w[k] - mx); s += pr[k]; }
    float inv = 1.f / s;
#pragma unroll
    for (int k = 0; k < 6; ++k) pr[k] *= inv;

    float eh[8]; unpack8(*(const uint4*)(ehb + (size_t)node * 512 + d0), eh);
    float nb[6][8];
#pragma unroll
    for (int k = 0; k < 6; ++k) unpack8(*(const uint4*)(etb + (size_t)idx[k] * 512 + d0), nb[k]);

    float kw[6] = {};
#pragma unroll
    for (int k = 0; k < 6; ++k) {
        float pk = pr[k];
#pragma unroll
        for (int j = 0; j < 8; ++j) {
            float ehr = pk * nb[k][j] + (1.f - pk) * eh[j];
            float g = tanhf(eh[j] + ehr);
            kw[k] += nb[k][j] * g;
        }
    }
#pragma unroll
    for (int k = 0; k < 6; ++k)
#pragma unroll
        for (int o = 1; o < 64; o <<= 1) kw[k] += __shfl_xor(kw[k], o, 64);
    float m2 = kw[0];
#pragma unroll
    for (int k = 1; k < 6; ++k) m2 = fmaxf(m2, kw[k]);
    float kp[6], s2 = 0.f;
#pragma unroll
    for (int k = 0; k < 6; ++k) { kp[k] = expf(kw[k] - m2); s2 += kp[k]; }
    float inv2 = 1.f / s2;
#pragma unroll
    for (int k = 0; k < 6; ++k) kp[k] *= inv2;

    float sv[8], pv[8];
#pragma unroll
    for (int j = 0; j < 8; ++j) {
        float en = 0.f;
#pragma unroll
        for (int k = 0; k < 6; ++k) en += kp[k] * nb[k][j];
        sv[j] = eh[j] + en;
        pv[j] = eh[j] * en;
    }
    *(uint4*)(sb + (size_t)node * 512 + d0) = pack8(sv);
    *(uint4*)(pb + (size_t)node * 512 + d0) = pack8(pv);
}

// ---- final: node-mean -> LN -> classifier ----
DEV float blocksum512(float v, float* red, int lane, int wid) {
#pragma unroll
    for (int o = 1; o < 64; o <<= 1) v += __shfl_xor(v, o, 64);
    __syncthreads();
    if (lane == 0) red[wid] = v;
    __syncthreads();
    float s = 0.f;
#pragma unroll
    for (int w2 = 0; w2 < 8; ++w2) s += red[w2];
    return s;
}

__global__ __launch_bounds__(512) void k_final(
    const float* __restrict__ colsum_emb, const float* __restrict__ ln_g,
    const float* __restrict__ ln_b, const float* __restrict__ cls_w,
    const float* __restrict__ cls_b, float* __restrict__ out) {
    __shared__ float red[8];
    const int t = threadIdx.x, lane = t & 63, wid = t >> 6;
    float h = colsum_emb[t] * (1.f / 8192.f);
    float mu = blocksum512(h, red, lane, wid) * (1.f / 512.f);
    float d = h - mu;
    float var = blocksum512(d * d, red, lane, wid) * (1.f / 512.f);
    float y = d * rsqrtf(var + 1e-5f) * ln_g[t] + ln_b[t];
    float s0 = blocksum512(y * cls_w[t * 2 + 0], red, lane, wid);
    float s1 = blocksum512(y * cls_w[t * 2 + 1], red, lane, wid);
    if (t == 0) { out[0] = s0 + cls_b[0]; out[1] = s1 + cls_b[1]; }
}

extern "C" void kernel_launch(void* const* d_in, const int* in_sizes, int n_in,
                              void* d_out, int out_size, void* d_ws, size_t ws_size,
                              hipStream_t stream) {
    (void)in_sizes; (void)n_in; (void)out_size; (void)ws_size;
    const float* feats = (const float*)d_in[0];
    const float* fc1_w = (const float*)d_in[1];
    const float* fc1_b = (const float*)d_in[2];
    const float* wh_w  = (const float*)d_in[3];
    const float* wh_b  = (const float*)d_in[4];
    const float* wt_w  = (const float*)d_in[5];
    const float* wt_b  = (const float*)d_in[6];
    const float* l1_w  = (const float*)d_in[7];
    const float* l1_b  = (const float*)d_in[8];
    const float* l2_w  = (const float*)d_in[9];
    const float* l2_b  = (const float*)d_in[10];
    const float* ln_g  = (const float*)d_in[11];
    const float* ln_b  = (const float*)d_in[12];
    const float* cls_w = (const float*)d_in[13];
    const float* cls_b = (const float*)d_in[14];

    char* ws = (char*)d_ws;
    size_t off = 0;
    auto alloc = [&](size_t bytes) {
        char* p = ws + off;
        off += (bytes + 255) & ~(size_t)255;
        return p;
    };
    unsigned short* fb   = (unsigned short*)alloc(8192ull * 384 * 2);
    unsigned short* xb   = (unsigned short*)alloc(8192ull * 512 * 2);
    unsigned short* ehb  = (unsigned short*)alloc(8192ull * 512 * 2);
    unsigned short* etb  = (unsigned short*)alloc(8192ull * 512 * 2);
    unsigned short* sb   = (unsigned short*)alloc(8192ull * 512 * 2);
    unsigned short* pb   = (unsigned short*)alloc(8192ull * 512 * 2);
    unsigned short* wfc1T = (unsigned short*)alloc(512ull * 384 * 2);
    unsigned short* whT  = (unsigned short*)alloc(512ull * 512 * 2);
    unsigned short* wtT  = (unsigned short*)alloc(512ull * 512 * 2);
    unsigned short* l1T  = (unsigned short*)alloc(512ull * 512 * 2);
    unsigned short* l2T  = (unsigned short*)alloc(512ull * 512 * 2);
    float* colsum     = (float*)alloc(512 * 4);
    float* colsum_emb = (float*)alloc(512 * 4);
    float* pw = (float*)alloc(8192ull * 16 * 6 * 4);
    int*   pi = (int*)alloc(8192ull * 16 * 6 * 4);
    float* tw = (float*)alloc(8192ull * 6 * 4);
    int*   ti = (int*)alloc(8192ull * 6 * 4);

    hipMemsetAsync(colsum, 0, 512 * 4, stream);
    hipMemsetAsync(colsum_emb, 0, 512 * 4, stream);

    k_conv_bf16<<<(8192 * 384 / 4 + 255) / 256, 256, 0, stream>>>(feats, fb, 8192 * 384);
    k_transpose_bf16<<<(512 * 384 + 255) / 256, 256, 0, stream>>>(fc1_w, wfc1T, 384, 512);
    k_transpose_bf16<<<(512 * 512 + 255) / 256, 256, 0, stream>>>(wh_w, whT, 512, 512);
    k_transpose_bf16<<<(512 * 512 + 255) / 256, 256, 0, stream>>>(wt_w, wtT, 512, 512);
    k_transpose_bf16<<<(512 * 512 + 255) / 256, 256, 0, stream>>>(l1_w, l1T, 512, 512);
    k_transpose_bf16<<<(512 * 512 + 255) / 256, 256, 0, stream>>>(l2_w, l2T, 512, 512);

    // x0 = lrelu(feats@fc1 + b), colsum(x0)
    k_gemm<1, 1><<<dim3(64, 4), 256, 0, stream>>>(fb, wfc1T, fc1_b, xb, colsum, 8192, 512, 384);
    // x = 0.5*(x0 + colmean)
    k_update_x<<<2048, 256, 0, stream>>>(xb, colsum);
    // e_h, e_t
    k_gemm<0, 0><<<dim3(64, 4), 256, 0, stream>>>(xb, whT, wh_b, ehb, nullptr, 8192, 512, 512);
    k_gemm<0, 0><<<dim3(64, 4), 256, 0, stream>>>(xb, wtT, wt_b, etb, nullptr, 8192, 512, 512);
    // attn logits + fused partial top-6 (16 col-splits), then merge
    k_attn_topk<<<dim3(64, 16), 256, 0, stream>>>(ehb, etb, pw, pi);
    k_merge_topk<<<32, 256, 0, stream>>>(pw, pi, tw, ti);
    // neighbor aggregation -> s = e_h + e_Nh, p = e_h * e_Nh (bf16)
    k_agg<<<2048, 256, 0, stream>>>(ehb, etb, tw, ti, sb, pb);
    // emb colsums (never materialize emb)
    k_gemm<1, 2><<<dim3(64, 4), 256, 0, stream>>>(sb, l1T, l1_b, nullptr, colsum_emb, 8192, 512, 512);
    k_gemm<1, 2><<<dim3(64, 4), 256, 0, stream>>>(pb, l2T, l2_b, nullptr, colsum_emb, 8192, 512, 512);
    // mean -> LN -> classifier
    k_final<<<1, 512, 0, stream>>>(colsum_emb, ln_g, ln_b, cls_w, cls_b, (float*)d_out);
}

// Round 4
// 273.282 us; speedup vs baseline: 1.6824x; 1.6824x over previous
//
#include <hip/hip_runtime.h>
#include <math.h>

#define DEV __device__ __forceinline__

// ---- MFMA fragment types (gfx950 16x16x32 bf16) ----
using frag_ab = __attribute__((ext_vector_type(8))) short;  // 8 bf16 (4 VGPRs)
using frag_cd = __attribute__((ext_vector_type(4))) float;  // 4 fp32

static constexpr float SCALE_C = 0.04419417382415922f;  // 512^-0.5

// ---- bf16 helpers (RNE) ----
DEV unsigned short f2bf(float f) {
    unsigned u = __float_as_uint(f);
    unsigned r = (u + 0x7FFFu + ((u >> 16) & 1u)) >> 16;
    return (unsigned short)r;
}
DEV float bf2f(unsigned short h) { return __uint_as_float(((unsigned)h) << 16); }

DEV void unpack8(uint4 q, float f[8]) {
    f[0] = bf2f((unsigned short)(q.x & 0xFFFFu)); f[1] = bf2f((unsigned short)(q.x >> 16));
    f[2] = bf2f((unsigned short)(q.y & 0xFFFFu)); f[3] = bf2f((unsigned short)(q.y >> 16));
    f[4] = bf2f((unsigned short)(q.z & 0xFFFFu)); f[5] = bf2f((unsigned short)(q.z >> 16));
    f[6] = bf2f((unsigned short)(q.w & 0xFFFFu)); f[7] = bf2f((unsigned short)(q.w >> 16));
}
DEV uint4 pack8(const float f[8]) {
    uint4 q;
    q.x = (unsigned)f2bf(f[0]) | ((unsigned)f2bf(f[1]) << 16);
    q.y = (unsigned)f2bf(f[2]) | ((unsigned)f2bf(f[3]) << 16);
    q.z = (unsigned)f2bf(f[4]) | ((unsigned)f2bf(f[5]) << 16);
    q.w = (unsigned)f2bf(f[6]) | ((unsigned)f2bf(f[7]) << 16);
    return q;
}

// ---- async global->LDS 16B (direct-to-LDS DMA; dest = wave base + lane*16) ----
DEV void gload_lds16(const void* g, void* l) {
    __builtin_amdgcn_global_load_lds(
        (const __attribute__((address_space(1))) void*)g,
        (__attribute__((address_space(3))) void*)l, 16, 0, 0);
}

// ---- elementwise converts ----
__global__ void k_conv_bf16(const float* __restrict__ s, unsigned short* __restrict__ d, int n) {
    int i = (blockIdx.x * 256 + threadIdx.x) * 4;
    if (i + 3 < n) {
        float4 v = *(const float4*)(s + i);
        ushort4 o;
        o.x = f2bf(v.x); o.y = f2bf(v.y); o.z = f2bf(v.z); o.w = f2bf(v.w);
        *(ushort4*)(d + i) = o;
    }
}

// src [K][N] f32 -> dst [N][K] bf16 (transposed weight for MFMA B-operand)
__global__ void k_transpose_bf16(const float* __restrict__ s, unsigned short* __restrict__ d, int K, int N) {
    int i = blockIdx.x * 256 + threadIdx.x;
    if (i >= K * N) return;
    int n = i / K, k = i - n * K;
    d[i] = f2bf(s[k * N + n]);
}

// ---- tile staging: 128 rows x 64 bf16 (16KB), XOR-swizzled layout (G4/rule 21):
// linear LDS dest (global_load_lds requirement) + inverse-swizzled per-lane
// global source; ds_read applies the same involution.
// 256 threads, 4 chunks of 4KB (32 rows each).
DEV void stage_async(const unsigned short* __restrict__ g, int ld, int k0, char* lds, int t) {
    const int sub = t >> 3;               // row within 32-row chunk
    const int b = (t & 7) << 4;           // physical byte col 0..112
    const int bs = b ^ ((sub & 7) << 4);  // swizzled source byte col
    const char* gb = (const char*)(g + k0) + (size_t)sub * (size_t)(ld * 2) + bs;
    char* lb = lds + ((t >> 6) << 10);    // wave-uniform LDS base
    const size_t rstep = (size_t)32 * (ld * 2);
#pragma unroll
    for (int r = 0; r < 4; ++r)
        gload_lds16(gb + r * rstep, lb + r * 4096);
}

// ---- one 128x128x64 MFMA step (2x2 waves, 4x4 frags each) ----
// bv streamed one fragment at a time to keep arch-VGPR pressure low.
DEV void mfma_tile(const char* As, const char* Bs, int lane, int wr, int wc, frag_cd (&acc)[4][4]) {
#pragma unroll
    for (int ks = 0; ks < 2; ++ks) {
        const int boff = ks * 64 + ((lane >> 4) << 4);
        frag_ab av[4];
#pragma unroll
        for (int f = 0; f < 4; ++f) {
            int ra = wr * 64 + f * 16 + (lane & 15);
            av[f] = *(const frag_ab*)(As + ra * 128 + (boff ^ ((ra & 7) << 4)));
        }
#pragma unroll
        for (int j = 0; j < 4; ++j) {
            int rb = wc * 64 + j * 16 + (lane & 15);
            frag_ab bv = *(const frag_ab*)(Bs + rb * 128 + (boff ^ ((rb & 7) << 4)));
#pragma unroll
            for (int i = 0; i < 4; ++i)
                acc[i][j] = __builtin_amdgcn_mfma_f32_16x16x32_bf16(av[i], bv, acc[i][j], 0, 0, 0);
        }
    }
}

// ---- generic bf16 GEMM: C = act(A @ BT^T + bias); EPI: 0=store, 1=store+colsum, 2=colsum only ----
template <int ACT, int EPI>
__global__ __launch_bounds__(256, 3) void k_gemm(
    const unsigned short* __restrict__ A, const unsigned short* __restrict__ BT,
    const float* __restrict__ bias, unsigned short* __restrict__ out,
    float* __restrict__ colsum, int M, int N, int K) {
    __shared__ __align__(16) char As[16384];
    __shared__ __align__(16) char Bs[16384];
    __shared__ float colacc[128];
    const int t = threadIdx.x;
    const int lane = t & 63, wid = t >> 6, wr = wid >> 1, wc = wid & 1;
    const int m0 = blockIdx.x * 128, n0 = blockIdx.y * 128;
    if (EPI >= 1 && t < 128) colacc[t] = 0.f;
    frag_cd acc[4][4] = {};
    for (int k0 = 0; k0 < K; k0 += 64) {
        __syncthreads();
        stage_async(A + (size_t)m0 * K, K, k0, As, t);
        stage_async(BT + (size_t)n0 * K, K, k0, Bs, t);
        __syncthreads();
        mfma_tile(As, Bs, lane, wr, wc, acc);
    }
    // epilogue
    float bval[4];
#pragma unroll
    for (int j = 0; j < 4; ++j) bval[j] = bias[n0 + wc * 64 + j * 16 + (lane & 15)];
#pragma unroll
    for (int i = 0; i < 4; ++i) {
#pragma unroll
        for (int j = 0; j < 4; ++j) {
            float cs = 0.f;
#pragma unroll
            for (int r = 0; r < 4; ++r) {
                float v = acc[i][j][r] + bval[j];
                if (ACT) v = v > 0.f ? v : 0.01f * v;
                if (EPI != 2) {
                    int row = m0 + wr * 64 + i * 16 + (lane >> 4) * 4 + r;
                    int col = n0 + wc * 64 + j * 16 + (lane & 15);
                    out[(size_t)row * N + col] = f2bf(v);
                }
                cs += v;
            }
            if (EPI >= 1) atomicAdd(&colacc[wc * 64 + j * 16 + (lane & 15)], cs);
        }
    }
    if (EPI >= 1) {
        __syncthreads();
        if (t < 128) atomicAdd(&colsum[n0 + t], colacc[t]);
    }
}

// ---- x = 0.5*(x + colmean) in-place on bf16 ----
__global__ void k_update_x(unsigned short* __restrict__ xb, const float* __restrict__ colsum) {
    int i = (blockIdx.x * 256 + threadIdx.x) * 8;
    uint4 q = *(const uint4*)(xb + i);
    float f[8]; unpack8(q, f);
    int c0 = i & 511;
#pragma unroll
    for (int j = 0; j < 8; ++j) f[j] = 0.5f * (f[j] + colsum[c0 + j] * (1.f / 8192.f));
    *(uint4*)(xb + i) = pack8(f);
}

// ---- branchless top-6 insert. Strict > with increasing-index scan order
// reproduces lax.top_k's value-desc / index-asc tie rule exactly.
DEV void topk6_ins(float (&v)[6], int (&ix)[6], float cv, int ci) {
    bool b[6];
#pragma unroll
    for (int j = 0; j < 6; ++j) b[j] = cv > v[j];
#pragma unroll
    for (int j = 5; j >= 1; --j) {
        v[j] = b[j] ? (b[j - 1] ? v[j - 1] : cv) : v[j];
        ix[j] = b[j] ? (b[j - 1] ? ix[j - 1] : ci) : ix[j];
    }
    v[0] = b[0] ? cv : v[0];
    ix[0] = b[0] ? ci : ix[0];
}

// ---- fused attn-logit GEMM + partial top-6 ----
// grid (64 row-blocks, 16 col-splits); each block: 128 rows x 512 cols.
// LDS: As/Bs (32KB) unioned with the S spill tile (128x68 f32 = 34.8KB) -> up to 4 blocks/CU.
__global__ __launch_bounds__(256, 3) void k_attn_topk(
    const unsigned short* __restrict__ ehb, const unsigned short* __restrict__ etb,
    float* __restrict__ pw, int* __restrict__ pi) {
    __shared__ __align__(16) char smem[34816];
    char* As = smem;
    char* Bs = smem + 16384;
    float* Stile = (float*)smem;  // 128 x 68 f32 (stride 68 -> 16B-aligned rows), dead during GEMM
    const int t = threadIdx.x;
    const int lane = t & 63, wid = t >> 6, wr = wid >> 1, wc = wid & 1;
    const int m0 = blockIdx.x * 128;
    const int csplit = blockIdx.y;
    const int srow = t >> 1, hh = t & 1;
    float tv[6]; int tix[6];
#pragma unroll
    for (int j = 0; j < 6; ++j) { tv[j] = -INFINITY; tix[j] = 0x7FFFFFFF; }

    for (int ct = 0; ct < 4; ++ct) {
        const int n0 = csplit * 512 + ct * 128;
        frag_cd acc[4][4] = {};
        for (int k0 = 0; k0 < 512; k0 += 64) {
            __syncthreads();  // protects prior Stile scan / prior tile reads
            stage_async(ehb + (size_t)m0 * 512, 512, k0, As, t);
            stage_async(etb + (size_t)n0 * 512, 512, k0, Bs, t);
            __syncthreads();  // compiler drains vmcnt(0) here (async loads done)
            mfma_tile(As, Bs, lane, wr, wc, acc);
        }
        // spill S-tile into (dead) As/Bs space in two 64-col chunks, scan top-6
#pragma unroll
        for (int ch = 0; ch < 2; ++ch) {
            __syncthreads();
            if (wc == ch) {
#pragma unroll
                for (int i = 0; i < 4; ++i)
#pragma unroll
                    for (int j = 0; j < 4; ++j)
#pragma unroll
                        for (int r = 0; r < 4; ++r) {
                            int row = wr * 64 + i * 16 + (lane >> 4) * 4 + r;
                            int col = j * 16 + (lane & 15);
                            Stile[row * 68 + col] = acc[i][j][r] * SCALE_C;
                        }
            }
            __syncthreads();
            // branchless scan: 8x float4 loads, 32 unconditional inserts
            const float* srowp = &Stile[srow * 68 + hh * 32];
            const int gbase = n0 + ch * 64 + hh * 32;
#pragma unroll 2
            for (int q = 0; q < 8; ++q) {
                float4 f4 = *(const float4*)(srowp + q * 4);
                topk6_ins(tv, tix, f4.x, gbase + q * 4 + 0);
                topk6_ins(tv, tix, f4.y, gbase + q * 4 + 1);
                topk6_ins(tv, tix, f4.z, gbase + q * 4 + 2);
                topk6_ins(tv, tix, f4.w, gbase + q * 4 + 3);
            }
        }
    }
    // merge the two half-row scanners via lane-pair shuffle (lanes 2k <-> 2k+1);
    // hh=0 (lower indices) is incumbent -> stable tie order preserved.
#pragma unroll
    for (int j = 0; j < 6; ++j) {
        float ov = __shfl_xor(tv[j], 1, 64);
        int oi = __shfl_xor(tix[j], 1, 64);
        if (hh == 0) topk6_ins(tv, tix, ov, oi);
    }
    if (hh == 0) {
        size_t o = ((size_t)(m0 + srow) * 16 + csplit) * 6;
#pragma unroll
        for (int j = 0; j < 6; ++j) { pw[o + j] = tv[j]; pi[o + j] = tix[j]; }
    }
}

// ---- merge 16 partial top-6 lists -> final top-6 per row ----
// processes csplits in increasing index order -> stable ties.
__global__ void k_merge_topk(const float* __restrict__ pw, const int* __restrict__ pi,
                             float* __restrict__ tw, int* __restrict__ ti) {
    int r = blockIdx.x * 256 + threadIdx.x;
    if (r >= 8192) return;
    float v[6]; int ix[6];
#pragma unroll
    for (int j = 0; j < 6; ++j) { v[j] = -INFINITY; ix[j] = 0x7FFFFFFF; }
    for (int s2 = 0; s2 < 16; ++s2) {
#pragma unroll
        for (int j = 0; j < 6; ++j) {
            size_t o = ((size_t)r * 16 + s2) * 6 + j;
            topk6_ins(v, ix, pw[o], pi[o]);
        }
    }
#pragma unroll
    for (int j = 0; j < 6; ++j) { tw[r * 6 + j] = v[j]; ti[r * 6 + j] = ix[j]; }
}

// ---- per-node neighbor aggregation: one wave per node ----
__global__ __launch_bounds__(256) void k_agg(
    const unsigned short* __restrict__ ehb, const unsigned short* __restrict__ etb,
    const float* __restrict__ tw, const int* __restrict__ ti,
    unsigned short* __restrict__ sb, unsigned short* __restrict__ pb) {
    const int t = threadIdx.x, lane = t & 63, wid = t >> 6;
    const int node = blockIdx.x * 4 + wid;
    const int d0 = lane * 8;
    float w[6]; int idx[6];
#pragma unroll
    for (int k = 0; k < 6; ++k) { w[k] = tw[node * 6 + k]; idx[k] = ti[node * 6 + k]; }
    float mx = w[0];
#pragma unroll
    for (int k = 1; k < 6; ++k) mx = fmaxf(mx, w[k]);
    float pr[6], s = 0.f;
#pragma unroll
    for (int k = 0; k < 6; ++k) { pr[k] = expf(w[k] - mx); s += pr[k]; }
    float inv = 1.f / s;
#pragma unroll
    for (int k = 0; k < 6; ++k) pr[k] *= inv;

    float eh[8]; unpack8(*(const uint4*)(ehb + (size_t)node * 512 + d0), eh);
    float nb[6][8];
#pragma unroll
    for (int k = 0; k < 6; ++k) unpack8(*(const uint4*)(etb + (size_t)idx[k] * 512 + d0), nb[k]);

    float kw[6] = {};
#pragma unroll
    for (int k = 0; k < 6; ++k) {
        float pk = pr[k];
#pragma unroll
        for (int j = 0; j < 8; ++j) {
            float ehr = pk * nb[k][j] + (1.f - pk) * eh[j];
            float g = tanhf(eh[j] + ehr);
            kw[k] += nb[k][j] * g;
        }
    }
#pragma unroll
    for (int k = 0; k < 6; ++k)
#pragma unroll
        for (int o = 1; o < 64; o <<= 1) kw[k] += __shfl_xor(kw[k], o, 64);
    float m2 = kw[0];
#pragma unroll
    for (int k = 1; k < 6; ++k) m2 = fmaxf(m2, kw[k]);
    float kp[6], s2 = 0.f;
#pragma unroll
    for (int k = 0; k < 6; ++k) { kp[k] = expf(kw[k] - m2); s2 += kp[k]; }
    float inv2 = 1.f / s2;
#pragma unroll
    for (int k = 0; k < 6; ++k) kp[k] *= inv2;

    float sv[8], pv[8];
#pragma unroll
    for (int j = 0; j < 8; ++j) {
        float en = 0.f;
#pragma unroll
        for (int k = 0; k < 6; ++k) en += kp[k] * nb[k][j];
        sv[j] = eh[j] + en;
        pv[j] = eh[j] * en;
    }
    *(uint4*)(sb + (size_t)node * 512 + d0) = pack8(sv);
    *(uint4*)(pb + (size_t)node * 512 + d0) = pack8(pv);
}

// ---- final: node-mean -> LN -> classifier ----
DEV float blocksum512(float v, float* red, int lane, int wid) {
#pragma unroll
    for (int o = 1; o < 64; o <<= 1) v += __shfl_xor(v, o, 64);
    __syncthreads();
    if (lane == 0) red[wid] = v;
    __syncthreads();
    float s = 0.f;
#pragma unroll
    for (int w2 = 0; w2 < 8; ++w2) s += red[w2];
    return s;
}

__global__ __launch_bounds__(512) void k_final(
    const float* __restrict__ colsum_emb, const float* __restrict__ ln_g,
    const float* __restrict__ ln_b, const float* __restrict__ cls_w,
    const float* __restrict__ cls_b, float* __restrict__ out) {
    __shared__ float red[8];
    const int t = threadIdx.x, lane = t & 63, wid = t >> 6;
    float h = colsum_emb[t] * (1.f / 8192.f);
    float mu = blocksum512(h, red, lane, wid) * (1.f / 512.f);
    float d = h - mu;
    float var = blocksum512(d * d, red, lane, wid) * (1.f / 512.f);
    float y = d * rsqrtf(var + 1e-5f) * ln_g[t] + ln_b[t];
    float s0 = blocksum512(y * cls_w[t * 2 + 0], red, lane, wid);
    float s1 = blocksum512(y * cls_w[t * 2 + 1], red, lane, wid);
    if (t == 0) { out[0] = s0 + cls_b[0]; out[1] = s1 + cls_b[1]; }
}

extern "C" void kernel_launch(void* const* d_in, const int* in_sizes, int n_in,
                              void* d_out, int out_size, void* d_ws, size_t ws_size,
                              hipStream_t stream) {
    (void)in_sizes; (void)n_in; (void)out_size; (void)ws_size;
    const float* feats = (const float*)d_in[0];
    const float* fc1_w = (const float*)d_in[1];
    const float* fc1_b = (const float*)d_in[2];
    const float* wh_w  = (const float*)d_in[3];
    const float* wh_b  = (const float*)d_in[4];
    const float* wt_w  = (const float*)d_in[5];
    const float* wt_b  = (const float*)d_in[6];
    const float* l1_w  = (const float*)d_in[7];
    const float* l1_b  = (const float*)d_in[8];
    const float* l2_w  = (const float*)d_in[9];
    const float* l2_b  = (const float*)d_in[10];
    const float* ln_g  = (const float*)d_in[11];
    const float* ln_b  = (const float*)d_in[12];
    const float* cls_w = (const float*)d_in[13];
    const float* cls_b = (const float*)d_in[14];

    char* ws = (char*)d_ws;
    size_t off = 0;
    auto alloc = [&](size_t bytes) {
        char* p = ws + off;
        off += (bytes + 255) & ~(size_t)255;
        return p;
    };
    unsigned short* fb   = (unsigned short*)alloc(8192ull * 384 * 2);
    unsigned short* xb   = (unsigned short*)alloc(8192ull * 512 * 2);
    unsigned short* ehb  = (unsigned short*)alloc(8192ull * 512 * 2);
    unsigned short* etb  = (unsigned short*)alloc(8192ull * 512 * 2);
    unsigned short* sb   = (unsigned short*)alloc(8192ull * 512 * 2);
    unsigned short* pb   = (unsigned short*)alloc(8192ull * 512 * 2);
    unsigned short* wfc1T = (unsigned short*)alloc(512ull * 384 * 2);
    unsigned short* whT  = (unsigned short*)alloc(512ull * 512 * 2);
    unsigned short* wtT  = (unsigned short*)alloc(512ull * 512 * 2);
    unsigned short* l1T  = (unsigned short*)alloc(512ull * 512 * 2);
    unsigned short* l2T  = (unsigned short*)alloc(512ull * 512 * 2);
    float* colsum     = (float*)alloc(512 * 4);
    float* colsum_emb = (float*)alloc(512 * 4);
    float* pw = (float*)alloc(8192ull * 16 * 6 * 4);
    int*   pi = (int*)alloc(8192ull * 16 * 6 * 4);
    float* tw = (float*)alloc(8192ull * 6 * 4);
    int*   ti = (int*)alloc(8192ull * 6 * 4);

    hipMemsetAsync(colsum, 0, 512 * 4, stream);
    hipMemsetAsync(colsum_emb, 0, 512 * 4, stream);

    k_conv_bf16<<<(8192 * 384 / 4 + 255) / 256, 256, 0, stream>>>(feats, fb, 8192 * 384);
    k_transpose_bf16<<<(512 * 384 + 255) / 256, 256, 0, stream>>>(fc1_w, wfc1T, 384, 512);
    k_transpose_bf16<<<(512 * 512 + 255) / 256, 256, 0, stream>>>(wh_w, whT, 512, 512);
    k_transpose_bf16<<<(512 * 512 + 255) / 256, 256, 0, stream>>>(wt_w, wtT, 512, 512);
    k_transpose_bf16<<<(512 * 512 + 255) / 256, 256, 0, stream>>>(l1_w, l1T, 512, 512);
    k_transpose_bf16<<<(512 * 512 + 255) / 256, 256, 0, stream>>>(l2_w, l2T, 512, 512);

    // x0 = lrelu(feats@fc1 + b), colsum(x0)
    k_gemm<1, 1><<<dim3(64, 4), 256, 0, stream>>>(fb, wfc1T, fc1_b, xb, colsum, 8192, 512, 384);
    // x = 0.5*(x0 + colmean)
    k_update_x<<<2048, 256, 0, stream>>>(xb, colsum);
    // e_h, e_t
    k_gemm<0, 0><<<dim3(64, 4), 256, 0, stream>>>(xb, whT, wh_b, ehb, nullptr, 8192, 512, 512);
    k_gemm<0, 0><<<dim3(64, 4), 256, 0, stream>>>(xb, wtT, wt_b, etb, nullptr, 8192, 512, 512);
    // attn logits + fused partial top-6 (16 col-splits), then merge
    k_attn_topk<<<dim3(64, 16), 256, 0, stream>>>(ehb, etb, pw, pi);
    k_merge_topk<<<32, 256, 0, stream>>>(pw, pi, tw, ti);
    // neighbor aggregation -> s = e_h + e_Nh, p = e_h * e_Nh (bf16)
    k_agg<<<2048, 256, 0, stream>>>(ehb, etb, tw, ti, sb, pb);
    // emb colsums (never materialize emb)
    k_gemm<1, 2><<<dim3(64, 4), 256, 0, stream>>>(sb, l1T, l1_b, nullptr, colsum_emb, 8192, 512, 512);
    k_gemm<1, 2><<<dim3(64, 4), 256, 0, stream>>>(pb, l2T, l2_b, nullptr, colsum_emb, 8192, 512, 512);
    // mean -> LN -> classifier
    k_final<<<1, 512, 0, stream>>>(colsum_emb, ln_g, ln_b, cls_w, cls_b, (float*)d_out);
}

// Round 5
// 223.100 us; speedup vs baseline: 2.0608x; 1.2249x over previous
//
#include <hip/hip_runtime.h>
#include <math.h>

#define DEV __device__ __forceinline__

// ---- MFMA fragment types (gfx950 16x16x32 bf16) ----
using frag_ab = __attribute__((ext_vector_type(8))) short;  // 8 bf16 (4 VGPRs)
using frag_cd = __attribute__((ext_vector_type(4))) float;  // 4 fp32

static constexpr float SCALE_C = 0.04419417382415922f;  // 512^-0.5

// ---- bf16 helpers (RNE) ----
DEV unsigned short f2bf(float f) {
    unsigned u = __float_as_uint(f);
    unsigned r = (u + 0x7FFFu + ((u >> 16) & 1u)) >> 16;
    return (unsigned short)r;
}
DEV float bf2f(unsigned short h) { return __uint_as_float(((unsigned)h) << 16); }

DEV void unpack8(uint4 q, float f[8]) {
    f[0] = bf2f((unsigned short)(q.x & 0xFFFFu)); f[1] = bf2f((unsigned short)(q.x >> 16));
    f[2] = bf2f((unsigned short)(q.y & 0xFFFFu)); f[3] = bf2f((unsigned short)(q.y >> 16));
    f[4] = bf2f((unsigned short)(q.z & 0xFFFFu)); f[5] = bf2f((unsigned short)(q.z >> 16));
    f[6] = bf2f((unsigned short)(q.w & 0xFFFFu)); f[7] = bf2f((unsigned short)(q.w >> 16));
}
DEV uint4 pack8(const float f[8]) {
    uint4 q;
    q.x = (unsigned)f2bf(f[0]) | ((unsigned)f2bf(f[1]) << 16);
    q.y = (unsigned)f2bf(f[2]) | ((unsigned)f2bf(f[3]) << 16);
    q.z = (unsigned)f2bf(f[4]) | ((unsigned)f2bf(f[5]) << 16);
    q.w = (unsigned)f2bf(f[6]) | ((unsigned)f2bf(f[7]) << 16);
    return q;
}

// ---- order-preserving float<->u32 (monotone key) ----
DEV unsigned mono(float f) {
    unsigned u = __float_as_uint(f);
    return u ^ ((unsigned)((int)u >> 31) | 0x80000000u);
}
DEV float unmono(unsigned k) {
    unsigned u = (k & 0x80000000u) ? (k & 0x7FFFFFFFu) : ~k;
    return __uint_as_float(u);
}

// ---- async global->LDS 16B (direct-to-LDS DMA; dest = wave base + lane*16) ----
DEV void gload_lds16(const void* g, void* l) {
    __builtin_amdgcn_global_load_lds(
        (const __attribute__((address_space(1))) void*)g,
        (__attribute__((address_space(3))) void*)l, 16, 0, 0);
}

// ---- elementwise converts ----
__global__ void k_conv_bf16(const float* __restrict__ s, unsigned short* __restrict__ d, int n) {
    int i = (blockIdx.x * 256 + threadIdx.x) * 4;
    if (i + 3 < n) {
        float4 v = *(const float4*)(s + i);
        ushort4 o;
        o.x = f2bf(v.x); o.y = f2bf(v.y); o.z = f2bf(v.z); o.w = f2bf(v.w);
        *(ushort4*)(d + i) = o;
    }
}

// src [K][N] f32 -> dst [N][K] bf16 (transposed weight for MFMA B-operand)
__global__ void k_transpose_bf16(const float* __restrict__ s, unsigned short* __restrict__ d, int K, int N) {
    int i = blockIdx.x * 256 + threadIdx.x;
    if (i >= K * N) return;
    int n = i / K, k = i - n * K;
    d[i] = f2bf(s[k * N + n]);
}

// ---- tile staging: 128 rows x 64 bf16 (16KB), XOR-swizzled layout (G4/rule 21):
// linear LDS dest (global_load_lds requirement) + inverse-swizzled per-lane
// global source; ds_read applies the same involution.
DEV void stage_async(const unsigned short* __restrict__ g, int ld, int k0, char* lds, int t) {
    const int sub = t >> 3;               // row within 32-row chunk
    const int b = (t & 7) << 4;           // physical byte col 0..112
    const int bs = b ^ ((sub & 7) << 4);  // swizzled source byte col
    const char* gb = (const char*)(g + k0) + (size_t)sub * (size_t)(ld * 2) + bs;
    char* lb = lds + ((t >> 6) << 10);    // wave-uniform LDS base
    const size_t rstep = (size_t)32 * (ld * 2);
#pragma unroll
    for (int r = 0; r < 4; ++r)
        gload_lds16(gb + r * rstep, lb + r * 4096);
}

// ---- one 128x128x64 MFMA step (2x2 waves, 4x4 frags each) ----
DEV void mfma_tile(const char* As, const char* Bs, int lane, int wr, int wc, frag_cd (&acc)[4][4]) {
#pragma unroll
    for (int ks = 0; ks < 2; ++ks) {
        const int boff = ks * 64 + ((lane >> 4) << 4);
        frag_ab av[4];
#pragma unroll
        for (int f = 0; f < 4; ++f) {
            int ra = wr * 64 + f * 16 + (lane & 15);
            av[f] = *(const frag_ab*)(As + ra * 128 + (boff ^ ((ra & 7) << 4)));
        }
#pragma unroll
        for (int j = 0; j < 4; ++j) {
            int rb = wc * 64 + j * 16 + (lane & 15);
            frag_ab bv = *(const frag_ab*)(Bs + rb * 128 + (boff ^ ((rb & 7) << 4)));
#pragma unroll
            for (int i = 0; i < 4; ++i)
                acc[i][j] = __builtin_amdgcn_mfma_f32_16x16x32_bf16(av[i], bv, acc[i][j], 0, 0, 0);
        }
    }
}

// ---- generic bf16 GEMM: C = act(A @ BT^T + bias); EPI: 0=store, 1=store+colsum, 2=colsum only ----
template <int ACT, int EPI>
__global__ __launch_bounds__(256, 3) void k_gemm(
    const unsigned short* __restrict__ A, const unsigned short* __restrict__ BT,
    const float* __restrict__ bias, unsigned short* __restrict__ out,
    float* __restrict__ colsum, int M, int N, int K) {
    __shared__ __align__(16) char As[16384];
    __shared__ __align__(16) char Bs[16384];
    __shared__ float colacc[128];
    const int t = threadIdx.x;
    const int lane = t & 63, wid = t >> 6, wr = wid >> 1, wc = wid & 1;
    const int m0 = blockIdx.x * 128, n0 = blockIdx.y * 128;
    if (EPI >= 1 && t < 128) colacc[t] = 0.f;
    frag_cd acc[4][4] = {};
    for (int k0 = 0; k0 < K; k0 += 64) {
        __syncthreads();
        stage_async(A + (size_t)m0 * K, K, k0, As, t);
        stage_async(BT + (size_t)n0 * K, K, k0, Bs, t);
        __syncthreads();
        mfma_tile(As, Bs, lane, wr, wc, acc);
    }
    // epilogue
    float bval[4];
#pragma unroll
    for (int j = 0; j < 4; ++j) bval[j] = bias[n0 + wc * 64 + j * 16 + (lane & 15)];
#pragma unroll
    for (int i = 0; i < 4; ++i) {
#pragma unroll
        for (int j = 0; j < 4; ++j) {
            float cs = 0.f;
#pragma unroll
            for (int r = 0; r < 4; ++r) {
                float v = acc[i][j][r] + bval[j];
                if (ACT) v = v > 0.f ? v : 0.01f * v;
                if (EPI != 2) {
                    int row = m0 + wr * 64 + i * 16 + (lane >> 4) * 4 + r;
                    int col = n0 + wc * 64 + j * 16 + (lane & 15);
                    out[(size_t)row * N + col] = f2bf(v);
                }
                cs += v;
            }
            if (EPI >= 1) atomicAdd(&colacc[wc * 64 + j * 16 + (lane & 15)], cs);
        }
    }
    if (EPI >= 1) {
        __syncthreads();
        if (t < 128) atomicAdd(&colsum[n0 + t], colacc[t]);
    }
}

// ---- x = 0.5*(x + colmean) in-place on bf16 ----
__global__ void k_update_x(unsigned short* __restrict__ xb, const float* __restrict__ colsum) {
    int i = (blockIdx.x * 256 + threadIdx.x) * 8;
    uint4 q = *(const uint4*)(xb + i);
    float f[8]; unpack8(q, f);
    int c0 = i & 511;
#pragma unroll
    for (int j = 0; j < 8; ++j) f[j] = 0.5f * (f[j] + colsum[c0 + j] * (1.f / 8192.f));
    *(uint4*)(xb + i) = pack8(f);
}

// ---- sorted-desc top-6 key list: insert via min/max chain (11 ops, dep depth 2) ----
DEV void kins(unsigned (&v)[6], unsigned k) {
    unsigned m1 = v[0] < k ? v[0] : k;
    unsigned m2 = v[1] < k ? v[1] : k;
    unsigned m3 = v[2] < k ? v[2] : k;
    unsigned m4 = v[3] < k ? v[3] : k;
    unsigned m5 = v[4] < k ? v[4] : k;
    v[0] = v[0] > k ? v[0] : k;
    v[1] = v[1] > m1 ? v[1] : m1;
    v[2] = v[2] > m2 ? v[2] : m2;
    v[3] = v[3] > m3 ? v[3] : m3;
    v[4] = v[4] > m4 ? v[4] : m4;
    v[5] = v[5] > m5 ? v[5] : m5;
}

// ---- fused attn-logit GEMM + partial top-6 (key-based) ----
// grid (64 row-blocks, 16 col-splits); each block: 128 rows x 512 cols.
// LDS: As/Bs (32KB) unioned with the key spill tile (128x68 u32 = 34.8KB).
__global__ __launch_bounds__(256, 3) void k_attn_topk(
    const unsigned short* __restrict__ ehb, const unsigned short* __restrict__ etb,
    unsigned* __restrict__ pk) {
    __shared__ __align__(16) char smem[34816];
    char* As = smem;
    char* Bs = smem + 16384;
    unsigned* Stile = (unsigned*)smem;  // 128 x 68 u32 keys, dead during GEMM
    const int t = threadIdx.x;
    const int lane = t & 63, wid = t >> 6, wr = wid >> 1, wc = wid & 1;
    const int m0 = blockIdx.x * 128;
    const int csplit = blockIdx.y;
    const int srow = t >> 1, hh = t & 1;
    unsigned ka[6] = {0, 0, 0, 0, 0, 0};  // key 0 < any real key
    unsigned kb[6] = {0, 0, 0, 0, 0, 0};

    for (int ct = 0; ct < 4; ++ct) {
        const int n0 = csplit * 512 + ct * 128;
        frag_cd acc[4][4] = {};
        for (int k0 = 0; k0 < 512; k0 += 64) {
            __syncthreads();  // protects prior Stile scan / prior tile reads
            stage_async(ehb + (size_t)m0 * 512, 512, k0, As, t);
            stage_async(etb + (size_t)n0 * 512, 512, k0, Bs, t);
            __syncthreads();  // drains vmcnt(0) (async loads complete)
            mfma_tile(As, Bs, lane, wr, wc, acc);
        }
        // spill keys into (dead) As/Bs space in two 64-col chunks, scan top-6
#pragma unroll
        for (int ch = 0; ch < 2; ++ch) {
            __syncthreads();
            if (wc == ch) {
                // colkey base: 8191 - (global col); col = n0+ch*64+j*16+(lane&15)
                const unsigned ckb = 8191u - (unsigned)(n0 + ch * 64 + (lane & 15));
#pragma unroll
                for (int i = 0; i < 4; ++i)
#pragma unroll
                    for (int j = 0; j < 4; ++j)
#pragma unroll
                        for (int r = 0; r < 4; ++r) {
                            int row = wr * 64 + i * 16 + (lane >> 4) * 4 + r;
                            int col = j * 16 + (lane & 15);
                            unsigned key = (mono(acc[i][j][r]) & 0xFFFFE000u) | (ckb - j * 16);
                            Stile[row * 68 + col] = key;
                        }
            }
            __syncthreads();
            // dual-list branchless scan: 8x uint4 loads, 32 min/max-chain inserts
            const uint4* srowp = (const uint4*)(Stile + srow * 68 + hh * 32);
#pragma unroll
            for (int q = 0; q < 8; ++q) {
                uint4 u = srowp[q];
                kins(ka, u.x); kins(kb, u.y);
                kins(ka, u.z); kins(kb, u.w);
            }
        }
    }
    // merge dual lists (kb into ka)
#pragma unroll
    for (int j = 0; j < 6; ++j) kins(ka, kb[j]);
    // merge the two half-row scanners via lane-pair shuffle (lanes 2k <-> 2k+1)
#pragma unroll
    for (int j = 0; j < 6; ++j) {
        unsigned ok = (unsigned)__shfl_xor((int)ka[j], 1, 64);
        if (hh == 0) kins(ka, ok);
    }
    if (hh == 0) {
        size_t o = ((size_t)(m0 + srow) * 16 + csplit) * 6;
#pragma unroll
        for (int j = 0; j < 6; ++j) pk[o + j] = ka[j];
    }
}

// ---- merge 16 partial top-6 key lists -> final top-6 per row; decode ----
__global__ void k_merge_topk(const unsigned* __restrict__ pk,
                             float* __restrict__ tw, int* __restrict__ ti) {
    int r = blockIdx.x * 256 + threadIdx.x;
    if (r >= 8192) return;
    unsigned v[6] = {0, 0, 0, 0, 0, 0};
    for (int s2 = 0; s2 < 16; ++s2) {
        const unsigned* p = pk + ((size_t)r * 16 + s2) * 6;
#pragma unroll
        for (int j = 0; j < 6; ++j) kins(v, p[j]);
    }
#pragma unroll
    for (int j = 0; j < 6; ++j) {
        tw[r * 6 + j] = unmono(v[j] & 0xFFFFE000u) * SCALE_C;
        ti[r * 6 + j] = 8191 - (int)(v[j] & 8191u);
    }
}

// ---- per-node neighbor aggregation: one wave per node ----
__global__ __launch_bounds__(256) void k_agg(
    const unsigned short* __restrict__ ehb, const unsigned short* __restrict__ etb,
    const float* __restrict__ tw, const int* __restrict__ ti,
    unsigned short* __restrict__ sb, unsigned short* __restrict__ pb) {
    const int t = threadIdx.x, lane = t & 63, wid = t >> 6;
    const int node = blockIdx.x * 4 + wid;
    const int d0 = lane * 8;
    float w[6]; int idx[6];
#pragma unroll
    for (int k = 0; k < 6; ++k) { w[k] = tw[node * 6 + k]; idx[k] = ti[node * 6 + k]; }
    float mx = w[0];
#pragma unroll
    for (int k = 1; k < 6; ++k) mx = fmaxf(mx, w[k]);
    float pr[6], s = 0.f;
#pragma unroll
    for (int k = 0; k < 6; ++k) { pr[k] = expf(w[k] - mx); s += pr[k]; }
    float inv = 1.f / s;
#pragma unroll
    for (int k = 0; k < 6; ++k) pr[k] *= inv;

    float eh[8]; unpack8(*(const uint4*)(ehb + (size_t)node * 512 + d0), eh);
    float nb[6][8];
#pragma unroll
    for (int k = 0; k < 6; ++k) unpack8(*(const uint4*)(etb + (size_t)idx[k] * 512 + d0), nb[k]);

    float kw[6] = {};
#pragma unroll
    for (int k = 0; k < 6; ++k) {
        float pk2 = pr[k];
#pragma unroll
        for (int j = 0; j < 8; ++j) {
            float ehr = pk2 * nb[k][j] + (1.f - pk2) * eh[j];
            float g = tanhf(eh[j] + ehr);
            kw[k] += nb[k][j] * g;
        }
    }
#pragma unroll
    for (int k = 0; k < 6; ++k)
#pragma unroll
        for (int o = 1; o < 64; o <<= 1) kw[k] += __shfl_xor(kw[k], o, 64);
    float m2 = kw[0];
#pragma unroll
    for (int k = 1; k < 6; ++k) m2 = fmaxf(m2, kw[k]);
    float kp[6], s2 = 0.f;
#pragma unroll
    for (int k = 0; k < 6; ++k) { kp[k] = expf(kw[k] - m2); s2 += kp[k]; }
    float inv2 = 1.f / s2;
#pragma unroll
    for (int k = 0; k < 6; ++k) kp[k] *= inv2;

    float sv[8], pv[8];
#pragma unroll
    for (int j = 0; j < 8; ++j) {
        float en = 0.f;
#pragma unroll
        for (int k = 0; k < 6; ++k) en += kp[k] * nb[k][j];
        sv[j] = eh[j] + en;
        pv[j] = eh[j] * en;
    }
    *(uint4*)(sb + (size_t)node * 512 + d0) = pack8(sv);
    *(uint4*)(pb + (size_t)node * 512 + d0) = pack8(pv);
}

// ---- final: node-mean -> LN -> classifier ----
DEV float blocksum512(float v, float* red, int lane, int wid) {
#pragma unroll
    for (int o = 1; o < 64; o <<= 1) v += __shfl_xor(v, o, 64);
    __syncthreads();
    if (lane == 0) red[wid] = v;
    __syncthreads();
    float s = 0.f;
#pragma unroll
    for (int w2 = 0; w2 < 8; ++w2) s += red[w2];
    return s;
}

__global__ __launch_bounds__(512) void k_final(
    const float* __restrict__ colsum_emb, const float* __restrict__ ln_g,
    const float* __restrict__ ln_b, const float* __restrict__ cls_w,
    const float* __restrict__ cls_b, float* __restrict__ out) {
    __shared__ float red[8];
    const int t = threadIdx.x, lane = t & 63, wid = t >> 6;
    float h = colsum_emb[t] * (1.f / 8192.f);
    float mu = blocksum512(h, red, lane, wid) * (1.f / 512.f);
    float d = h - mu;
    float var = blocksum512(d * d, red, lane, wid) * (1.f / 512.f);
    float y = d * rsqrtf(var + 1e-5f) * ln_g[t] + ln_b[t];
    float s0 = blocksum512(y * cls_w[t * 2 + 0], red, lane, wid);
    float s1 = blocksum512(y * cls_w[t * 2 + 1], red, lane, wid);
    if (t == 0) { out[0] = s0 + cls_b[0]; out[1] = s1 + cls_b[1]; }
}

extern "C" void kernel_launch(void* const* d_in, const int* in_sizes, int n_in,
                              void* d_out, int out_size, void* d_ws, size_t ws_size,
                              hipStream_t stream) {
    (void)in_sizes; (void)n_in; (void)out_size; (void)ws_size;
    const float* feats = (const float*)d_in[0];
    const float* fc1_w = (const float*)d_in[1];
    const float* fc1_b = (const float*)d_in[2];
    const float* wh_w  = (const float*)d_in[3];
    const float* wh_b  = (const float*)d_in[4];
    const float* wt_w  = (const float*)d_in[5];
    const float* wt_b  = (const float*)d_in[6];
    const float* l1_w  = (const float*)d_in[7];
    const float* l1_b  = (const float*)d_in[8];
    const float* l2_w  = (const float*)d_in[9];
    const float* l2_b  = (const float*)d_in[10];
    const float* ln_g  = (const float*)d_in[11];
    const float* ln_b  = (const float*)d_in[12];
    const float* cls_w = (const float*)d_in[13];
    const float* cls_b = (const float*)d_in[14];

    char* ws = (char*)d_ws;
    size_t off = 0;
    auto alloc = [&](size_t bytes) {
        char* p = ws + off;
        off += (bytes + 255) & ~(size_t)255;
        return p;
    };
    unsigned short* fb   = (unsigned short*)alloc(8192ull * 384 * 2);
    unsigned short* xb   = (unsigned short*)alloc(8192ull * 512 * 2);
    unsigned short* ehb  = (unsigned short*)alloc(8192ull * 512 * 2);
    unsigned short* etb  = (unsigned short*)alloc(8192ull * 512 * 2);
    unsigned short* sb   = (unsigned short*)alloc(8192ull * 512 * 2);
    unsigned short* pb   = (unsigned short*)alloc(8192ull * 512 * 2);
    unsigned short* wfc1T = (unsigned short*)alloc(512ull * 384 * 2);
    unsigned short* whT  = (unsigned short*)alloc(512ull * 512 * 2);
    unsigned short* wtT  = (unsigned short*)alloc(512ull * 512 * 2);
    unsigned short* l1T  = (unsigned short*)alloc(512ull * 512 * 2);
    unsigned short* l2T  = (unsigned short*)alloc(512ull * 512 * 2);
    float* colsum     = (float*)alloc(512 * 4);
    float* colsum_emb = (float*)alloc(512 * 4);
    unsigned* pk = (unsigned*)alloc(8192ull * 16 * 6 * 4);
    float* tw = (float*)alloc(8192ull * 6 * 4);
    int*   ti = (int*)alloc(8192ull * 6 * 4);

    hipMemsetAsync(colsum, 0, 512 * 4, stream);
    hipMemsetAsync(colsum_emb, 0, 512 * 4, stream);

    k_conv_bf16<<<(8192 * 384 / 4 + 255) / 256, 256, 0, stream>>>(feats, fb, 8192 * 384);
    k_transpose_bf16<<<(512 * 384 + 255) / 256, 256, 0, stream>>>(fc1_w, wfc1T, 384, 512);
    k_transpose_bf16<<<(512 * 512 + 255) / 256, 256, 0, stream>>>(wh_w, whT, 512, 512);
    k_transpose_bf16<<<(512 * 512 + 255) / 256, 256, 0, stream>>>(wt_w, wtT, 512, 512);
    k_transpose_bf16<<<(512 * 512 + 255) / 256, 256, 0, stream>>>(l1_w, l1T, 512, 512);
    k_transpose_bf16<<<(512 * 512 + 255) / 256, 256, 0, stream>>>(l2_w, l2T, 512, 512);

    // x0 = lrelu(feats@fc1 + b), colsum(x0)
    k_gemm<1, 1><<<dim3(64, 4), 256, 0, stream>>>(fb, wfc1T, fc1_b, xb, colsum, 8192, 512, 384);
    // x = 0.5*(x0 + colmean)
    k_update_x<<<2048, 256, 0, stream>>>(xb, colsum);
    // e_h, e_t
    k_gemm<0, 0><<<dim3(64, 4), 256, 0, stream>>>(xb, whT, wh_b, ehb, nullptr, 8192, 512, 512);
    k_gemm<0, 0><<<dim3(64, 4), 256, 0, stream>>>(xb, wtT, wt_b, etb, nullptr, 8192, 512, 512);
    // attn logits + fused partial top-6 (16 col-splits), then merge+decode
    k_attn_topk<<<dim3(64, 16), 256, 0, stream>>>(ehb, etb, pk);
    k_merge_topk<<<32, 256, 0, stream>>>(pk, tw, ti);
    // neighbor aggregation -> s = e_h + e_Nh, p = e_h * e_Nh (bf16)
    k_agg<<<2048, 256, 0, stream>>>(ehb, etb, tw, ti, sb, pb);
    // emb colsums (never materialize emb)
    k_gemm<1, 2><<<dim3(64, 4), 256, 0, stream>>>(sb, l1T, l1_b, nullptr, colsum_emb, 8192, 512, 512);
    k_gemm<1, 2><<<dim3(64, 4), 256, 0, stream>>>(pb, l2T, l2_b, nullptr, colsum_emb, 8192, 512, 512);
    // mean -> LN -> classifier
    k_final<<<1, 512, 0, stream>>>(colsum_emb, ln_g, ln_b, cls_w, cls_b, (float*)d_out);
}

// Round 6
// 220.229 us; speedup vs baseline: 2.0876x; 1.0130x over previous
//
#include <hip/hip_runtime.h>
#include <math.h>

#define DEV __device__ __forceinline__

// ---- MFMA fragment types (gfx950 16x16x32 bf16) ----
using frag_ab = __attribute__((ext_vector_type(8))) short;  // 8 bf16 (4 VGPRs)
using frag_cd = __attribute__((ext_vector_type(4))) float;  // 4 fp32

static constexpr float SCALE_C = 0.04419417382415922f;  // 512^-0.5

// ---- bf16 helpers (RNE) ----
DEV unsigned short f2bf(float f) {
    unsigned u = __float_as_uint(f);
    unsigned r = (u + 0x7FFFu + ((u >> 16) & 1u)) >> 16;
    return (unsigned short)r;
}
DEV float bf2f(unsigned short h) { return __uint_as_float(((unsigned)h) << 16); }

DEV void unpack8(uint4 q, float f[8]) {
    f[0] = bf2f((unsigned short)(q.x & 0xFFFFu)); f[1] = bf2f((unsigned short)(q.x >> 16));
    f[2] = bf2f((unsigned short)(q.y & 0xFFFFu)); f[3] = bf2f((unsigned short)(q.y >> 16));
    f[4] = bf2f((unsigned short)(q.z & 0xFFFFu)); f[5] = bf2f((unsigned short)(q.z >> 16));
    f[6] = bf2f((unsigned short)(q.w & 0xFFFFu)); f[7] = bf2f((unsigned short)(q.w >> 16));
}
DEV uint4 pack8(const float f[8]) {
    uint4 q;
    q.x = (unsigned)f2bf(f[0]) | ((unsigned)f2bf(f[1]) << 16);
    q.y = (unsigned)f2bf(f[2]) | ((unsigned)f2bf(f[3]) << 16);
    q.z = (unsigned)f2bf(f[4]) | ((unsigned)f2bf(f[5]) << 16);
    q.w = (unsigned)f2bf(f[6]) | ((unsigned)f2bf(f[7]) << 16);
    return q;
}

// ---- order-preserving float<->u32 (monotone key) ----
DEV unsigned mono(float f) {
    unsigned u = __float_as_uint(f);
    return u ^ ((unsigned)((int)u >> 31) | 0x80000000u);
}
DEV float unmono(unsigned k) {
    unsigned u = (k & 0x80000000u) ? (k & 0x7FFFFFFFu) : ~k;
    return __uint_as_float(u);
}

// ---- async global->LDS 16B (direct-to-LDS DMA; dest = wave base + lane*16) ----
DEV void gload_lds16(const void* g, void* l) {
    __builtin_amdgcn_global_load_lds(
        (const __attribute__((address_space(1))) void*)g,
        (__attribute__((address_space(3))) void*)l, 16, 0, 0);
}

// ---- elementwise converts ----
__global__ void k_conv_bf16(const float* __restrict__ s, unsigned short* __restrict__ d, int n) {
    int i = (blockIdx.x * 256 + threadIdx.x) * 4;
    if (i + 3 < n) {
        float4 v = *(const float4*)(s + i);
        ushort4 o;
        o.x = f2bf(v.x); o.y = f2bf(v.y); o.z = f2bf(v.z); o.w = f2bf(v.w);
        *(ushort4*)(d + i) = o;
    }
}

// src [K][N] f32 -> dst [N][K] bf16 (transposed weight for MFMA B-operand)
__global__ void k_transpose_bf16(const float* __restrict__ s, unsigned short* __restrict__ d, int K, int N) {
    int i = blockIdx.x * 256 + threadIdx.x;
    if (i >= K * N) return;
    int n = i / K, k = i - n * K;
    d[i] = f2bf(s[k * N + n]);
}

// ---- tile staging: 128 rows x 64 bf16 (16KB), XOR-swizzled layout (G4/rule 21):
// linear LDS dest (global_load_lds requirement) + inverse-swizzled per-lane
// global source; ds_read applies the same involution.
DEV void stage_async(const unsigned short* __restrict__ g, int ld, int k0, char* lds, int t) {
    const int sub = t >> 3;               // row within 32-row chunk
    const int b = (t & 7) << 4;           // physical byte col 0..112
    const int bs = b ^ ((sub & 7) << 4);  // swizzled source byte col
    const char* gb = (const char*)(g + k0) + (size_t)sub * (size_t)(ld * 2) + bs;
    char* lb = lds + ((t >> 6) << 10);    // wave-uniform LDS base
    const size_t rstep = (size_t)32 * (ld * 2);
#pragma unroll
    for (int r = 0; r < 4; ++r)
        gload_lds16(gb + r * rstep, lb + r * 4096);
}

// ---- one 128x128x64 MFMA step (2x2 waves, 4x4 frags each) ----
DEV void mfma_tile(const char* As, const char* Bs, int lane, int wr, int wc, frag_cd (&acc)[4][4]) {
#pragma unroll
    for (int ks = 0; ks < 2; ++ks) {
        const int boff = ks * 64 + ((lane >> 4) << 4);
        frag_ab av[4];
#pragma unroll
        for (int f = 0; f < 4; ++f) {
            int ra = wr * 64 + f * 16 + (lane & 15);
            av[f] = *(const frag_ab*)(As + ra * 128 + (boff ^ ((ra & 7) << 4)));
        }
#pragma unroll
        for (int j = 0; j < 4; ++j) {
            int rb = wc * 64 + j * 16 + (lane & 15);
            frag_ab bv = *(const frag_ab*)(Bs + rb * 128 + (boff ^ ((rb & 7) << 4)));
#pragma unroll
            for (int i = 0; i < 4; ++i)
                acc[i][j] = __builtin_amdgcn_mfma_f32_16x16x32_bf16(av[i], bv, acc[i][j], 0, 0, 0);
        }
    }
}

// ---- generic bf16 GEMM, double-buffered 2-phase pipeline; blockIdx.z selects job.
// C = act(A @ BT^T + bias); EPI: 0=store, 1=store+colsum, 2=colsum only ----
template <int ACT, int EPI>
__global__ __launch_bounds__(256, 2) void k_gemm(
    const unsigned short* __restrict__ A0, const unsigned short* __restrict__ A1,
    const unsigned short* __restrict__ B0, const unsigned short* __restrict__ B1,
    const float* __restrict__ bias0, const float* __restrict__ bias1,
    unsigned short* __restrict__ out0, unsigned short* __restrict__ out1,
    float* __restrict__ colsum, int M, int N, int K) {
    __shared__ __align__(16) char smem[65536];  // As0|As1|Bs0|Bs1
    __shared__ float colacc[128];
    const int z = blockIdx.z;
    const unsigned short* A = z ? A1 : A0;
    const unsigned short* BT = z ? B1 : B0;
    const float* bias = z ? bias1 : bias0;
    unsigned short* out = z ? out1 : out0;
    const int t = threadIdx.x;
    const int lane = t & 63, wid = t >> 6, wr = wid >> 1, wc = wid & 1;
    const int m0 = blockIdx.x * 128, n0 = blockIdx.y * 128;
    if (EPI >= 1 && t < 128) colacc[t] = 0.f;
    const unsigned short* Ap = A + (size_t)m0 * K;
    const unsigned short* Bp = BT + (size_t)n0 * K;
    frag_cd acc[4][4] = {};
    const int nt = K >> 6;
    // 2-phase: stage(next) issued before mfma(cur); __syncthreads' implicit
    // vmcnt(0) drain lands after MFMA covered the (L2-resident) load latency.
    stage_async(Ap, K, 0, smem, t);
    stage_async(Bp, K, 0, smem + 32768, t);
    __syncthreads();
    for (int tt = 0; tt < nt; ++tt) {
        const int cur = tt & 1;
        if (tt + 1 < nt) {
            stage_async(Ap, K, (tt + 1) * 64, smem + ((cur ^ 1) << 14), t);
            stage_async(Bp, K, (tt + 1) * 64, smem + 32768 + ((cur ^ 1) << 14), t);
        }
        mfma_tile(smem + (cur << 14), smem + 32768 + (cur << 14), lane, wr, wc, acc);
        __syncthreads();
    }
    // epilogue
    float bval[4];
#pragma unroll
    for (int j = 0; j < 4; ++j) bval[j] = bias[n0 + wc * 64 + j * 16 + (lane & 15)];
#pragma unroll
    for (int i = 0; i < 4; ++i) {
#pragma unroll
        for (int j = 0; j < 4; ++j) {
            float cs = 0.f;
#pragma unroll
            for (int r = 0; r < 4; ++r) {
                float v = acc[i][j][r] + bval[j];
                if (ACT) v = v > 0.f ? v : 0.01f * v;
                if (EPI != 2) {
                    int row = m0 + wr * 64 + i * 16 + (lane >> 4) * 4 + r;
                    int col = n0 + wc * 64 + j * 16 + (lane & 15);
                    out[(size_t)row * N + col] = f2bf(v);
                }
                cs += v;
            }
            if (EPI >= 1) atomicAdd(&colacc[wc * 64 + j * 16 + (lane & 15)], cs);
        }
    }
    if (EPI >= 1) {
        __syncthreads();
        if (t < 128) atomicAdd(&colsum[n0 + t], colacc[t]);
    }
}

// ---- x = 0.5*(x + colmean) in-place on bf16 ----
__global__ void k_update_x(unsigned short* __restrict__ xb, const float* __restrict__ colsum) {
    int i = (blockIdx.x * 256 + threadIdx.x) * 8;
    uint4 q = *(const uint4*)(xb + i);
    float f[8]; unpack8(q, f);
    int c0 = i & 511;
#pragma unroll
    for (int j = 0; j < 8; ++j) f[j] = 0.5f * (f[j] + colsum[c0 + j] * (1.f / 8192.f));
    *(uint4*)(xb + i) = pack8(f);
}

// ---- sorted-desc top-6 key list: insert via min/max chain (11 ops, dep depth 2) ----
DEV void kins(unsigned (&v)[6], unsigned k) {
    unsigned m1 = v[0] < k ? v[0] : k;
    unsigned m2 = v[1] < k ? v[1] : k;
    unsigned m3 = v[2] < k ? v[2] : k;
    unsigned m4 = v[3] < k ? v[3] : k;
    unsigned m5 = v[4] < k ? v[4] : k;
    v[0] = v[0] > k ? v[0] : k;
    v[1] = v[1] > m1 ? v[1] : m1;
    v[2] = v[2] > m2 ? v[2] : m2;
    v[3] = v[3] > m3 ? v[3] : m3;
    v[4] = v[4] > m4 ? v[4] : m4;
    v[5] = v[5] > m5 ? v[5] : m5;
}

// ---- fused attn-logit GEMM + partial top-6 (key-based), 2-phase dbuf pipeline ----
// grid (64 row-blocks, 16 col-splits); each block: 128 rows x 512 cols.
// LDS 64KB: As0|As1|Bs0|Bs1; key spill tile (128x68 u32 = 34.8KB) unions the
// dead dbuf space during the scan phase.
__global__ __launch_bounds__(256, 2) void k_attn_topk(
    const unsigned short* __restrict__ ehb, const unsigned short* __restrict__ etb,
    unsigned* __restrict__ pk) {
    __shared__ __align__(16) char smem[65536];
    unsigned* Stile = (unsigned*)smem;  // 128 x 68 u32 keys, dead during GEMM
    const int t = threadIdx.x;
    const int lane = t & 63, wid = t >> 6, wr = wid >> 1, wc = wid & 1;
    const int m0 = blockIdx.x * 128;
    const int csplit = blockIdx.y;
    const int srow = t >> 1, hh = t & 1;
    const unsigned short* Ap = ehb + (size_t)m0 * 512;
    unsigned ka[6] = {0, 0, 0, 0, 0, 0};  // key 0 < any real key
    unsigned kb[6] = {0, 0, 0, 0, 0, 0};

    for (int ct = 0; ct < 4; ++ct) {
        const int n0 = csplit * 512 + ct * 128;
        const unsigned short* Bp = etb + (size_t)n0 * 512;
        frag_cd acc[4][4] = {};
        __syncthreads();  // prior ct's Stile scan complete before restaging
        stage_async(Ap, 512, 0, smem, t);
        stage_async(Bp, 512, 0, smem + 32768, t);
        __syncthreads();
#pragma unroll
        for (int tt = 0; tt < 8; ++tt) {
            const int cur = tt & 1;
            if (tt < 7) {
                stage_async(Ap, 512, (tt + 1) * 64, smem + ((cur ^ 1) << 14), t);
                stage_async(Bp, 512, (tt + 1) * 64, smem + 32768 + ((cur ^ 1) << 14), t);
            }
            mfma_tile(smem + (cur << 14), smem + 32768 + (cur << 14), lane, wr, wc, acc);
            __syncthreads();
        }
        // spill keys into (dead) dbuf space in two 64-col chunks, scan top-6
#pragma unroll
        for (int ch = 0; ch < 2; ++ch) {
            __syncthreads();
            if (wc == ch) {
                // colkey base: 8191 - (global col); col = n0+ch*64+j*16+(lane&15)
                const unsigned ckb = 8191u - (unsigned)(n0 + ch * 64 + (lane & 15));
#pragma unroll
                for (int i = 0; i < 4; ++i)
#pragma unroll
                    for (int j = 0; j < 4; ++j)
#pragma unroll
                        for (int r = 0; r < 4; ++r) {
                            int row = wr * 64 + i * 16 + (lane >> 4) * 4 + r;
                            int col = j * 16 + (lane & 15);
                            unsigned key = (mono(acc[i][j][r]) & 0xFFFFE000u) | (ckb - j * 16);
                            Stile[row * 68 + col] = key;
                        }
            }
            __syncthreads();
            // dual-list branchless scan: 8x uint4 loads, 32 min/max-chain inserts
            const uint4* srowp = (const uint4*)(Stile + srow * 68 + hh * 32);
#pragma unroll
            for (int q = 0; q < 8; ++q) {
                uint4 u = srowp[q];
                kins(ka, u.x); kins(kb, u.y);
                kins(ka, u.z); kins(kb, u.w);
            }
        }
    }
    // merge dual lists (kb into ka)
#pragma unroll
    for (int j = 0; j < 6; ++j) kins(ka, kb[j]);
    // merge the two half-row scanners via lane-pair shuffle (lanes 2k <-> 2k+1)
#pragma unroll
    for (int j = 0; j < 6; ++j) {
        unsigned ok = (unsigned)__shfl_xor((int)ka[j], 1, 64);
        if (hh == 0) kins(ka, ok);
    }
    if (hh == 0) {
        size_t o = ((size_t)(m0 + srow) * 16 + csplit) * 6;
#pragma unroll
        for (int j = 0; j < 6; ++j) pk[o + j] = ka[j];
    }
}

// ---- merge 16 partial top-6 key lists -> final top-6 per row; decode ----
__global__ void k_merge_topk(const unsigned* __restrict__ pk,
                             float* __restrict__ tw, int* __restrict__ ti) {
    int r = blockIdx.x * 256 + threadIdx.x;
    if (r >= 8192) return;
    unsigned v[6] = {0, 0, 0, 0, 0, 0};
    for (int s2 = 0; s2 < 16; ++s2) {
        const unsigned* p = pk + ((size_t)r * 16 + s2) * 6;
#pragma unroll
        for (int j = 0; j < 6; ++j) kins(v, p[j]);
    }
#pragma unroll
    for (int j = 0; j < 6; ++j) {
        tw[r * 6 + j] = unmono(v[j] & 0xFFFFE000u) * SCALE_C;
        ti[r * 6 + j] = 8191 - (int)(v[j] & 8191u);
    }
}

// ---- per-node neighbor aggregation: one wave per node ----
__global__ __launch_bounds__(256) void k_agg(
    const unsigned short* __restrict__ ehb, const unsigned short* __restrict__ etb,
    const float* __restrict__ tw, const int* __restrict__ ti,
    unsigned short* __restrict__ sb, unsigned short* __restrict__ pb) {
    const int t = threadIdx.x, lane = t & 63, wid = t >> 6;
    const int node = blockIdx.x * 4 + wid;
    const int d0 = lane * 8;
    float w[6]; int idx[6];
#pragma unroll
    for (int k = 0; k < 6; ++k) { w[k] = tw[node * 6 + k]; idx[k] = ti[node * 6 + k]; }
    float mx = w[0];
#pragma unroll
    for (int k = 1; k < 6; ++k) mx = fmaxf(mx, w[k]);
    float pr[6], s = 0.f;
#pragma unroll
    for (int k = 0; k < 6; ++k) { pr[k] = expf(w[k] - mx); s += pr[k]; }
    float inv = 1.f / s;
#pragma unroll
    for (int k = 0; k < 6; ++k) pr[k] *= inv;

    float eh[8]; unpack8(*(const uint4*)(ehb + (size_t)node * 512 + d0), eh);
    float nb[6][8];
#pragma unroll
    for (int k = 0; k < 6; ++k) unpack8(*(const uint4*)(etb + (size_t)idx[k] * 512 + d0), nb[k]);

    float kw[6] = {};
#pragma unroll
    for (int k = 0; k < 6; ++k) {
        float pk2 = pr[k];
#pragma unroll
        for (int j = 0; j < 8; ++j) {
            float ehr = pk2 * nb[k][j] + (1.f - pk2) * eh[j];
            float g = tanhf(eh[j] + ehr);
            kw[k] += nb[k][j] * g;
        }
    }
#pragma unroll
    for (int k = 0; k < 6; ++k)
#pragma unroll
        for (int o = 1; o < 64; o <<= 1) kw[k] += __shfl_xor(kw[k], o, 64);
    float m2 = kw[0];
#pragma unroll
    for (int k = 1; k < 6; ++k) m2 = fmaxf(m2, kw[k]);
    float kp[6], s2 = 0.f;
#pragma unroll
    for (int k = 0; k < 6; ++k) { kp[k] = expf(kw[k] - m2); s2 += kp[k]; }
    float inv2 = 1.f / s2;
#pragma unroll
    for (int k = 0; k < 6; ++k) kp[k] *= inv2;

    float sv[8], pv[8];
#pragma unroll
    for (int j = 0; j < 8; ++j) {
        float en = 0.f;
#pragma unroll
        for (int k = 0; k < 6; ++k) en += kp[k] * nb[k][j];
        sv[j] = eh[j] + en;
        pv[j] = eh[j] * en;
    }
    *(uint4*)(sb + (size_t)node * 512 + d0) = pack8(sv);
    *(uint4*)(pb + (size_t)node * 512 + d0) = pack8(pv);
}

// ---- final: node-mean -> LN -> classifier ----
DEV float blocksum512(float v, float* red, int lane, int wid) {
#pragma unroll
    for (int o = 1; o < 64; o <<= 1) v += __shfl_xor(v, o, 64);
    __syncthreads();
    if (lane == 0) red[wid] = v;
    __syncthreads();
    float s = 0.f;
#pragma unroll
    for (int w2 = 0; w2 < 8; ++w2) s += red[w2];
    return s;
}

__global__ __launch_bounds__(512) void k_final(
    const float* __restrict__ colsum_emb, const float* __restrict__ ln_g,
    const float* __restrict__ ln_b, const float* __restrict__ cls_w,
    const float* __restrict__ cls_b, float* __restrict__ out) {
    __shared__ float red[8];
    const int t = threadIdx.x, lane = t & 63, wid = t >> 6;
    float h = colsum_emb[t] * (1.f / 8192.f);
    float mu = blocksum512(h, red, lane, wid) * (1.f / 512.f);
    float d = h - mu;
    float var = blocksum512(d * d, red, lane, wid) * (1.f / 512.f);
    float y = d * rsqrtf(var + 1e-5f) * ln_g[t] + ln_b[t];
    float s0 = blocksum512(y * cls_w[t * 2 + 0], red, lane, wid);
    float s1 = blocksum512(y * cls_w[t * 2 + 1], red, lane, wid);
    if (t == 0) { out[0] = s0 + cls_b[0]; out[1] = s1 + cls_b[1]; }
}

extern "C" void kernel_launch(void* const* d_in, const int* in_sizes, int n_in,
                              void* d_out, int out_size, void* d_ws, size_t ws_size,
                              hipStream_t stream) {
    (void)in_sizes; (void)n_in; (void)out_size; (void)ws_size;
    const float* feats = (const float*)d_in[0];
    const float* fc1_w = (const float*)d_in[1];
    const float* fc1_b = (const float*)d_in[2];
    const float* wh_w  = (const float*)d_in[3];
    const float* wh_b  = (const float*)d_in[4];
    const float* wt_w  = (const float*)d_in[5];
    const float* wt_b  = (const float*)d_in[6];
    const float* l1_w  = (const float*)d_in[7];
    const float* l1_b  = (const float*)d_in[8];
    const float* l2_w  = (const float*)d_in[9];
    const float* l2_b  = (const float*)d_in[10];
    const float* ln_g  = (const float*)d_in[11];
    const float* ln_b  = (const float*)d_in[12];
    const float* cls_w = (const float*)d_in[13];
    const float* cls_b = (const float*)d_in[14];

    char* ws = (char*)d_ws;
    size_t off = 0;
    auto alloc = [&](size_t bytes) {
        char* p = ws + off;
        off += (bytes + 255) & ~(size_t)255;
        return p;
    };
    unsigned short* fb   = (unsigned short*)alloc(8192ull * 384 * 2);
    unsigned short* xb   = (unsigned short*)alloc(8192ull * 512 * 2);
    unsigned short* ehb  = (unsigned short*)alloc(8192ull * 512 * 2);
    unsigned short* etb  = (unsigned short*)alloc(8192ull * 512 * 2);
    unsigned short* sb   = (unsigned short*)alloc(8192ull * 512 * 2);
    unsigned short* pb   = (unsigned short*)alloc(8192ull * 512 * 2);
    unsigned short* wfc1T = (unsigned short*)alloc(512ull * 384 * 2);
    unsigned short* whT  = (unsigned short*)alloc(512ull * 512 * 2);
    unsigned short* wtT  = (unsigned short*)alloc(512ull * 512 * 2);
    unsigned short* l1T  = (unsigned short*)alloc(512ull * 512 * 2);
    unsigned short* l2T  = (unsigned short*)alloc(512ull * 512 * 2);
    float* colsum     = (float*)alloc(512 * 4);
    float* colsum_emb = (float*)alloc(512 * 4);
    unsigned* pk = (unsigned*)alloc(8192ull * 16 * 6 * 4);
    float* tw = (float*)alloc(8192ull * 6 * 4);
    int*   ti = (int*)alloc(8192ull * 6 * 4);

    hipMemsetAsync(colsum, 0, 512 * 4, stream);
    hipMemsetAsync(colsum_emb, 0, 512 * 4, stream);

    k_conv_bf16<<<(8192 * 384 / 4 + 255) / 256, 256, 0, stream>>>(feats, fb, 8192 * 384);
    k_transpose_bf16<<<(512 * 384 + 255) / 256, 256, 0, stream>>>(fc1_w, wfc1T, 384, 512);
    k_transpose_bf16<<<(512 * 512 + 255) / 256, 256, 0, stream>>>(wh_w, whT, 512, 512);
    k_transpose_bf16<<<(512 * 512 + 255) / 256, 256, 0, stream>>>(wt_w, wtT, 512, 512);
    k_transpose_bf16<<<(512 * 512 + 255) / 256, 256, 0, stream>>>(l1_w, l1T, 512, 512);
    k_transpose_bf16<<<(512 * 512 + 255) / 256, 256, 0, stream>>>(l2_w, l2T, 512, 512);

    // x0 = lrelu(feats@fc1 + b), colsum(x0)
    k_gemm<1, 1><<<dim3(64, 4, 1), 256, 0, stream>>>(
        fb, fb, wfc1T, wfc1T, fc1_b, fc1_b, xb, xb, colsum, 8192, 512, 384);
    // x = 0.5*(x0 + colmean)
    k_update_x<<<2048, 256, 0, stream>>>(xb, colsum);
    // e_h and e_t in one dual launch (z selects job)
    k_gemm<0, 0><<<dim3(64, 4, 2), 256, 0, stream>>>(
        xb, xb, whT, wtT, wh_b, wt_b, ehb, etb, nullptr, 8192, 512, 512);
    // attn logits + fused partial top-6 (16 col-splits), then merge+decode
    k_attn_topk<<<dim3(64, 16), 256, 0, stream>>>(ehb, etb, pk);
    k_merge_topk<<<32, 256, 0, stream>>>(pk, tw, ti);
    // neighbor aggregation -> s = e_h + e_Nh, p = e_h * e_Nh (bf16)
    k_agg<<<2048, 256, 0, stream>>>(ehb, etb, tw, ti, sb, pb);
    // emb colsums in one dual launch (never materialize emb)
    k_gemm<1, 2><<<dim3(64, 4, 2), 256, 0, stream>>>(
        sb, pb, l1T, l2T, l1_b, l2_b, nullptr, nullptr, colsum_emb, 8192, 512, 512);
    // mean -> LN -> classifier
    k_final<<<1, 512, 0, stream>>>(colsum_emb, ln_g, ln_b, cls_w, cls_b, (float*)d_out);
}

// Round 7
// 195.631 us; speedup vs baseline: 2.3501x; 1.1257x over previous
//
#include <hip/hip_runtime.h>
#include <math.h>

#define DEV __device__ __forceinline__

// ---- MFMA fragment types (gfx950 16x16x32 bf16) ----
using frag_ab = __attribute__((ext_vector_type(8))) short;  // 8 bf16 (4 VGPRs)
using frag_cd = __attribute__((ext_vector_type(4))) float;  // 4 fp32

static constexpr float SCALE_C = 0.04419417382415922f;  // 512^-0.5

// ---- bf16 helpers (RNE) ----
DEV unsigned short f2bf(float f) {
    unsigned u = __float_as_uint(f);
    unsigned r = (u + 0x7FFFu + ((u >> 16) & 1u)) >> 16;
    return (unsigned short)r;
}
DEV float bf2f(unsigned short h) { return __uint_as_float(((unsigned)h) << 16); }

DEV void unpack8(uint4 q, float f[8]) {
    f[0] = bf2f((unsigned short)(q.x & 0xFFFFu)); f[1] = bf2f((unsigned short)(q.x >> 16));
    f[2] = bf2f((unsigned short)(q.y & 0xFFFFu)); f[3] = bf2f((unsigned short)(q.y >> 16));
    f[4] = bf2f((unsigned short)(q.z & 0xFFFFu)); f[5] = bf2f((unsigned short)(q.z >> 16));
    f[6] = bf2f((unsigned short)(q.w & 0xFFFFu)); f[7] = bf2f((unsigned short)(q.w >> 16));
}
DEV uint4 pack8(const float f[8]) {
    uint4 q;
    q.x = (unsigned)f2bf(f[0]) | ((unsigned)f2bf(f[1]) << 16);
    q.y = (unsigned)f2bf(f[2]) | ((unsigned)f2bf(f[3]) << 16);
    q.z = (unsigned)f2bf(f[4]) | ((unsigned)f2bf(f[5]) << 16);
    q.w = (unsigned)f2bf(f[6]) | ((unsigned)f2bf(f[7]) << 16);
    return q;
}

// ---- order-preserving float<->u32 (monotone key) ----
DEV unsigned mono(float f) {
    unsigned u = __float_as_uint(f);
    return u ^ ((unsigned)((int)u >> 31) | 0x80000000u);
}
DEV float unmono(unsigned k) {
    unsigned u = (k & 0x80000000u) ? (k & 0x7FFFFFFFu) : ~k;
    return __uint_as_float(u);
}

// ---- async global->LDS 16B (direct-to-LDS DMA; dest = wave base + lane*16) ----
DEV void gload_lds16(const void* g, void* l) {
    __builtin_amdgcn_global_load_lds(
        (const __attribute__((address_space(1))) void*)g,
        (__attribute__((address_space(3))) void*)l, 16, 0, 0);
}

// ---- elementwise converts ----
__global__ void k_conv_bf16(const float* __restrict__ s, unsigned short* __restrict__ d, int n) {
    int i = (blockIdx.x * 256 + threadIdx.x) * 4;
    if (i + 3 < n) {
        float4 v = *(const float4*)(s + i);
        ushort4 o;
        o.x = f2bf(v.x); o.y = f2bf(v.y); o.z = f2bf(v.z); o.w = f2bf(v.w);
        *(ushort4*)(d + i) = o;
    }
}

// src [K][N] f32 -> dst [N][K] bf16 (transposed weight for MFMA B-operand)
__global__ void k_transpose_bf16(const float* __restrict__ s, unsigned short* __restrict__ d, int K, int N) {
    int i = blockIdx.x * 256 + threadIdx.x;
    if (i >= K * N) return;
    int n = i / K, k = i - n * K;
    d[i] = f2bf(s[k * N + n]);
}

// ---- tile staging: 128 rows x 64 bf16 (16KB), XOR-swizzled layout (G4/rule 21):
// linear LDS dest (global_load_lds requirement) + inverse-swizzled per-lane
// global source; ds_read applies the same involution.
DEV void stage_async(const unsigned short* __restrict__ g, int ld, int k0, char* lds, int t) {
    const int sub = t >> 3;               // row within 32-row chunk
    const int b = (t & 7) << 4;           // physical byte col 0..112
    const int bs = b ^ ((sub & 7) << 4);  // swizzled source byte col
    const char* gb = (const char*)(g + k0) + (size_t)sub * (size_t)(ld * 2) + bs;
    char* lb = lds + ((t >> 6) << 10);    // wave-uniform LDS base
    const size_t rstep = (size_t)32 * (ld * 2);
#pragma unroll
    for (int r = 0; r < 4; ++r)
        gload_lds16(gb + r * rstep, lb + r * 4096);
}

// ---- one 128x128x64 MFMA step (2x2 waves, 4x4 frags each) ----
DEV void mfma_tile(const char* As, const char* Bs, int lane, int wr, int wc, frag_cd (&acc)[4][4]) {
#pragma unroll
    for (int ks = 0; ks < 2; ++ks) {
        const int boff = ks * 64 + ((lane >> 4) << 4);
        frag_ab av[4];
#pragma unroll
        for (int f = 0; f < 4; ++f) {
            int ra = wr * 64 + f * 16 + (lane & 15);
            av[f] = *(const frag_ab*)(As + ra * 128 + (boff ^ ((ra & 7) << 4)));
        }
#pragma unroll
        for (int j = 0; j < 4; ++j) {
            int rb = wc * 64 + j * 16 + (lane & 15);
            frag_ab bv = *(const frag_ab*)(Bs + rb * 128 + (boff ^ ((rb & 7) << 4)));
#pragma unroll
            for (int i = 0; i < 4; ++i)
                acc[i][j] = __builtin_amdgcn_mfma_f32_16x16x32_bf16(av[i], bv, acc[i][j], 0, 0, 0);
        }
    }
}

// ---- generic bf16 GEMM, 2-stage software pipeline (static buffers, unroll 1);
// blockIdx.z selects job. C = act(A @ BT^T + bias); EPI: 0=store, 1=store+colsum, 2=colsum only ----
template <int ACT, int EPI>
__global__ __launch_bounds__(256, 2) void k_gemm(
    const unsigned short* __restrict__ A0, const unsigned short* __restrict__ A1,
    const unsigned short* __restrict__ B0, const unsigned short* __restrict__ B1,
    const float* __restrict__ bias0, const float* __restrict__ bias1,
    unsigned short* __restrict__ out0, unsigned short* __restrict__ out1,
    float* __restrict__ colsum, int M, int N, int K) {
    __shared__ __align__(16) char smem[65536];
    __shared__ float colacc[128];
    char* sA0 = smem;
    char* sA1 = smem + 16384;
    char* sB0 = smem + 32768;
    char* sB1 = smem + 49152;
    const int z = blockIdx.z;
    const unsigned short* A = z ? A1 : A0;
    const unsigned short* BT = z ? B1 : B0;
    const float* bias = z ? bias1 : bias0;
    unsigned short* out = z ? out1 : out0;
    const int t = threadIdx.x;
    const int lane = t & 63, wid = t >> 6, wr = wid >> 1, wc = wid & 1;
    const int m0 = blockIdx.x * 128, n0 = blockIdx.y * 128;
    if (EPI >= 1 && t < 128) colacc[t] = 0.f;
    const unsigned short* Ap = A + (size_t)m0 * K;
    const unsigned short* Bp = BT + (size_t)n0 * K;
    frag_cd acc[4][4] = {};
    const int nt = K >> 6;  // even, >= 4
    // 2-stage pipeline: stage(next) issued before mfma(cur); __syncthreads'
    // implicit vmcnt(0) drain lands after MFMA covered the L2 load latency.
    stage_async(Ap, K, 0, sA0, t);
    stage_async(Bp, K, 0, sB0, t);
    __syncthreads();
#pragma unroll 1
    for (int tt = 0; tt < nt - 2; tt += 2) {
        stage_async(Ap, K, (tt + 1) * 64, sA1, t);
        stage_async(Bp, K, (tt + 1) * 64, sB1, t);
        mfma_tile(sA0, sB0, lane, wr, wc, acc);
        __syncthreads();
        stage_async(Ap, K, (tt + 2) * 64, sA0, t);
        stage_async(Bp, K, (tt + 2) * 64, sB0, t);
        mfma_tile(sA1, sB1, lane, wr, wc, acc);
        __syncthreads();
    }
    stage_async(Ap, K, (nt - 1) * 64, sA1, t);
    stage_async(Bp, K, (nt - 1) * 64, sB1, t);
    mfma_tile(sA0, sB0, lane, wr, wc, acc);
    __syncthreads();
    mfma_tile(sA1, sB1, lane, wr, wc, acc);
    // epilogue (acc only; no LDS reuse hazards)
    float bval[4];
#pragma unroll
    for (int j = 0; j < 4; ++j) bval[j] = bias[n0 + wc * 64 + j * 16 + (lane & 15)];
#pragma unroll
    for (int i = 0; i < 4; ++i) {
#pragma unroll
        for (int j = 0; j < 4; ++j) {
            float cs = 0.f;
#pragma unroll
            for (int r = 0; r < 4; ++r) {
                float v = acc[i][j][r] + bval[j];
                if (ACT) v = v > 0.f ? v : 0.01f * v;
                if (EPI != 2) {
                    int row = m0 + wr * 64 + i * 16 + (lane >> 4) * 4 + r;
                    int col = n0 + wc * 64 + j * 16 + (lane & 15);
                    out[(size_t)row * N + col] = f2bf(v);
                }
                cs += v;
            }
            if (EPI >= 1) atomicAdd(&colacc[wc * 64 + j * 16 + (lane & 15)], cs);
        }
    }
    if (EPI >= 1) {
        __syncthreads();
        if (t < 128) atomicAdd(&colsum[n0 + t], colacc[t]);
    }
}

// ---- x = 0.5*(x + colmean) in-place on bf16 ----
__global__ void k_update_x(unsigned short* __restrict__ xb, const float* __restrict__ colsum) {
    int i = (blockIdx.x * 256 + threadIdx.x) * 8;
    uint4 q = *(const uint4*)(xb + i);
    float f[8]; unpack8(q, f);
    int c0 = i & 511;
#pragma unroll
    for (int j = 0; j < 8; ++j) f[j] = 0.5f * (f[j] + colsum[c0 + j] * (1.f / 8192.f));
    *(uint4*)(xb + i) = pack8(f);
}

// ---- sorted-desc top-6 key list: insert via min/max chain (11 ops, dep depth 2) ----
DEV void kins(unsigned (&v)[6], unsigned k) {
    unsigned m1 = v[0] < k ? v[0] : k;
    unsigned m2 = v[1] < k ? v[1] : k;
    unsigned m3 = v[2] < k ? v[2] : k;
    unsigned m4 = v[3] < k ? v[3] : k;
    unsigned m5 = v[4] < k ? v[4] : k;
    v[0] = v[0] > k ? v[0] : k;
    v[1] = v[1] > m1 ? v[1] : m1;
    v[2] = v[2] > m2 ? v[2] : m2;
    v[3] = v[3] > m3 ? v[3] : m3;
    v[4] = v[4] > m4 ? v[4] : m4;
    v[5] = v[5] > m5 ? v[5] : m5;
}

// ---- fused attn-logit GEMM + partial top-6 (key-based), 2-stage pipeline ----
// grid (64 row-blocks, 16 col-splits); each block: 128 rows x 512 cols.
// LDS 64KB: sA0|sA1|sB0|sB1; key spill tile (128x68 u32 = 34.8KB) unions the
// dead buffer space during the scan phase (barrier-separated).
__global__ __launch_bounds__(256, 2) void k_attn_topk(
    const unsigned short* __restrict__ ehb, const unsigned short* __restrict__ etb,
    unsigned* __restrict__ pk) {
    __shared__ __align__(16) char smem[65536];
    char* sA0 = smem;
    char* sA1 = smem + 16384;
    char* sB0 = smem + 32768;
    char* sB1 = smem + 49152;
    unsigned* Stile = (unsigned*)smem;  // 128 x 68 u32 keys, dead during GEMM
    const int t = threadIdx.x;
    const int lane = t & 63, wid = t >> 6, wr = wid >> 1, wc = wid & 1;
    const int m0 = blockIdx.x * 128;
    const int csplit = blockIdx.y;
    const int srow = t >> 1, hh = t & 1;
    const unsigned short* Ap = ehb + (size_t)m0 * 512;
    unsigned ka[6] = {0, 0, 0, 0, 0, 0};  // key 0 < any real key
    unsigned kb[6] = {0, 0, 0, 0, 0, 0};

    for (int ct = 0; ct < 4; ++ct) {
        const int n0 = csplit * 512 + ct * 128;
        const unsigned short* Bp = etb + (size_t)n0 * 512;
        frag_cd acc[4][4] = {};
        __syncthreads();  // prior ct's Stile scan complete before restaging
        stage_async(Ap, 512, 0, sA0, t);
        stage_async(Bp, 512, 0, sB0, t);
        __syncthreads();
#pragma unroll 1
        for (int p = 0; p < 3; ++p) {
            stage_async(Ap, 512, (2 * p + 1) * 64, sA1, t);
            stage_async(Bp, 512, (2 * p + 1) * 64, sB1, t);
            mfma_tile(sA0, sB0, lane, wr, wc, acc);
            __syncthreads();
            stage_async(Ap, 512, (2 * p + 2) * 64, sA0, t);
            stage_async(Bp, 512, (2 * p + 2) * 64, sB0, t);
            mfma_tile(sA1, sB1, lane, wr, wc, acc);
            __syncthreads();
        }
        stage_async(Ap, 512, 7 * 64, sA1, t);
        stage_async(Bp, 512, 7 * 64, sB1, t);
        mfma_tile(sA0, sB0, lane, wr, wc, acc);
        __syncthreads();
        mfma_tile(sA1, sB1, lane, wr, wc, acc);
        __syncthreads();  // all mfma reads done before key spill overwrites buffers
        // spill keys into (dead) buffer space in two 64-col chunks, scan top-6
#pragma unroll
        for (int ch = 0; ch < 2; ++ch) {
            if (wc == ch) {
                // colkey base: 8191 - (global col); col = n0+ch*64+j*16+(lane&15)
                const unsigned ckb = 8191u - (unsigned)(n0 + ch * 64 + (lane & 15));
#pragma unroll
                for (int i = 0; i < 4; ++i)
#pragma unroll
                    for (int j = 0; j < 4; ++j)
#pragma unroll
                        for (int r = 0; r < 4; ++r) {
                            int row = wr * 64 + i * 16 + (lane >> 4) * 4 + r;
                            int col = j * 16 + (lane & 15);
                            unsigned key = (mono(acc[i][j][r]) & 0xFFFFE000u) | (ckb - j * 16);
                            Stile[row * 68 + col] = key;
                        }
            }
            __syncthreads();
            // dual-list branchless scan: 8x uint4 loads, 32 min/max-chain inserts
            const uint4* srowp = (const uint4*)(Stile + srow * 68 + hh * 32);
#pragma unroll
            for (int q = 0; q < 8; ++q) {
                uint4 u = srowp[q];
                kins(ka, u.x); kins(kb, u.y);
                kins(ka, u.z); kins(kb, u.w);
            }
            __syncthreads();  // scan done before next chunk's spill
        }
    }
    // merge dual lists (kb into ka)
#pragma unroll
    for (int j = 0; j < 6; ++j) kins(ka, kb[j]);
    // merge the two half-row scanners via lane-pair shuffle (lanes 2k <-> 2k+1)
#pragma unroll
    for (int j = 0; j < 6; ++j) {
        unsigned ok = (unsigned)__shfl_xor((int)ka[j], 1, 64);
        if (hh == 0) kins(ka, ok);
    }
    if (hh == 0) {
        size_t o = ((size_t)(m0 + srow) * 16 + csplit) * 6;
#pragma unroll
        for (int j = 0; j < 6; ++j) pk[o + j] = ka[j];
    }
}

// ---- merge 16 partial top-6 key lists -> final top-6 per row; decode ----
__global__ void k_merge_topk(const unsigned* __restrict__ pk,
                             float* __restrict__ tw, int* __restrict__ ti) {
    int r = blockIdx.x * 256 + threadIdx.x;
    if (r >= 8192) return;
    unsigned v[6] = {0, 0, 0, 0, 0, 0};
    for (int s2 = 0; s2 < 16; ++s2) {
        const unsigned* p = pk + ((size_t)r * 16 + s2) * 6;
#pragma unroll
        for (int j = 0; j < 6; ++j) kins(v, p[j]);
    }
#pragma unroll
    for (int j = 0; j < 6; ++j) {
        tw[r * 6 + j] = unmono(v[j] & 0xFFFFE000u) * SCALE_C;
        ti[r * 6 + j] = 8191 - (int)(v[j] & 8191u);
    }
}

// ---- per-node neighbor aggregation: one wave per node ----
__global__ __launch_bounds__(256) void k_agg(
    const unsigned short* __restrict__ ehb, const unsigned short* __restrict__ etb,
    const float* __restrict__ tw, const int* __restrict__ ti,
    unsigned short* __restrict__ sb, unsigned short* __restrict__ pb) {
    const int t = threadIdx.x, lane = t & 63, wid = t >> 6;
    const int node = blockIdx.x * 4 + wid;
    const int d0 = lane * 8;
    float w[6]; int idx[6];
#pragma unroll
    for (int k = 0; k < 6; ++k) { w[k] = tw[node * 6 + k]; idx[k] = ti[node * 6 + k]; }
    float mx = w[0];
#pragma unroll
    for (int k = 1; k < 6; ++k) mx = fmaxf(mx, w[k]);
    float pr[6], s = 0.f;
#pragma unroll
    for (int k = 0; k < 6; ++k) { pr[k] = expf(w[k] - mx); s += pr[k]; }
    float inv = 1.f / s;
#pragma unroll
    for (int k = 0; k < 6; ++k) pr[k] *= inv;

    float eh[8]; unpack8(*(const uint4*)(ehb + (size_t)node * 512 + d0), eh);
    float nb[6][8];
#pragma unroll
    for (int k = 0; k < 6; ++k) unpack8(*(const uint4*)(etb + (size_t)idx[k] * 512 + d0), nb[k]);

    float kw[6] = {};
#pragma unroll
    for (int k = 0; k < 6; ++k) {
        float pk2 = pr[k];
#pragma unroll
        for (int j = 0; j < 8; ++j) {
            float ehr = pk2 * nb[k][j] + (1.f - pk2) * eh[j];
            float g = tanhf(eh[j] + ehr);
            kw[k] += nb[k][j] * g;
        }
    }
#pragma unroll
    for (int k = 0; k < 6; ++k)
#pragma unroll
        for (int o = 1; o < 64; o <<= 1) kw[k] += __shfl_xor(kw[k], o, 64);
    float m2 = kw[0];
#pragma unroll
    for (int k = 1; k < 6; ++k) m2 = fmaxf(m2, kw[k]);
    float kp[6], s2 = 0.f;
#pragma unroll
    for (int k = 0; k < 6; ++k) { kp[k] = expf(kw[k] - m2); s2 += kp[k]; }
    float inv2 = 1.f / s2;
#pragma unroll
    for (int k = 0; k < 6; ++k) kp[k] *= inv2;

    float sv[8], pv[8];
#pragma unroll
    for (int j = 0; j < 8; ++j) {
        float en = 0.f;
#pragma unroll
        for (int k = 0; k < 6; ++k) en += kp[k] * nb[k][j];
        sv[j] = eh[j] + en;
        pv[j] = eh[j] * en;
    }
    *(uint4*)(sb + (size_t)node * 512 + d0) = pack8(sv);
    *(uint4*)(pb + (size_t)node * 512 + d0) = pack8(pv);
}

// ---- final: node-mean -> LN -> classifier ----
DEV float blocksum512(float v, float* red, int lane, int wid) {
#pragma unroll
    for (int o = 1; o < 64; o <<= 1) v += __shfl_xor(v, o, 64);
    __syncthreads();
    if (lane == 0) red[wid] = v;
    __syncthreads();
    float s = 0.f;
#pragma unroll
    for (int w2 = 0; w2 < 8; ++w2) s += red[w2];
    return s;
}

__global__ __launch_bounds__(512) void k_final(
    const float* __restrict__ colsum_emb, const float* __restrict__ ln_g,
    const float* __restrict__ ln_b, const float* __restrict__ cls_w,
    const float* __restrict__ cls_b, float* __restrict__ out) {
    __shared__ float red[8];
    const int t = threadIdx.x, lane = t & 63, wid = t >> 6;
    float h = colsum_emb[t] * (1.f / 8192.f);
    float mu = blocksum512(h, red, lane, wid) * (1.f / 512.f);
    float d = h - mu;
    float var = blocksum512(d * d, red, lane, wid) * (1.f / 512.f);
    float y = d * rsqrtf(var + 1e-5f) * ln_g[t] + ln_b[t];
    float s0 = blocksum512(y * cls_w[t * 2 + 0], red, lane, wid);
    float s1 = blocksum512(y * cls_w[t * 2 + 1], red, lane, wid);
    if (t == 0) { out[0] = s0 + cls_b[0]; out[1] = s1 + cls_b[1]; }
}

extern "C" void kernel_launch(void* const* d_in, const int* in_sizes, int n_in,
                              void* d_out, int out_size, void* d_ws, size_t ws_size,
                              hipStream_t stream) {
    (void)in_sizes; (void)n_in; (void)out_size; (void)ws_size;
    const float* feats = (const float*)d_in[0];
    const float* fc1_w = (const float*)d_in[1];
    const float* fc1_b = (const float*)d_in[2];
    const float* wh_w  = (const float*)d_in[3];
    const float* wh_b  = (const float*)d_in[4];
    const float* wt_w  = (const float*)d_in[5];
    const float* wt_b  = (const float*)d_in[6];
    const float* l1_w  = (const float*)d_in[7];
    const float* l1_b  = (const float*)d_in[8];
    const float* l2_w  = (const float*)d_in[9];
    const float* l2_b  = (const float*)d_in[10];
    const float* ln_g  = (const float*)d_in[11];
    const float* ln_b  = (const float*)d_in[12];
    const float* cls_w = (const float*)d_in[13];
    const float* cls_b = (const float*)d_in[14];

    char* ws = (char*)d_ws;
    size_t off = 0;
    auto alloc = [&](size_t bytes) {
        char* p = ws + off;
        off += (bytes + 255) & ~(size_t)255;
        return p;
    };
    unsigned short* fb   = (unsigned short*)alloc(8192ull * 384 * 2);
    unsigned short* xb   = (unsigned short*)alloc(8192ull * 512 * 2);
    unsigned short* ehb  = (unsigned short*)alloc(8192ull * 512 * 2);
    unsigned short* etb  = (unsigned short*)alloc(8192ull * 512 * 2);
    unsigned short* sb   = (unsigned short*)alloc(8192ull * 512 * 2);
    unsigned short* pb   = (unsigned short*)alloc(8192ull * 512 * 2);
    unsigned short* wfc1T = (unsigned short*)alloc(512ull * 384 * 2);
    unsigned short* whT  = (unsigned short*)alloc(512ull * 512 * 2);
    unsigned short* wtT  = (unsigned short*)alloc(512ull * 512 * 2);
    unsigned short* l1T  = (unsigned short*)alloc(512ull * 512 * 2);
    unsigned short* l2T  = (unsigned short*)alloc(512ull * 512 * 2);
    float* colsum     = (float*)alloc(512 * 4);
    float* colsum_emb = (float*)alloc(512 * 4);
    unsigned* pk = (unsigned*)alloc(8192ull * 16 * 6 * 4);
    float* tw = (float*)alloc(8192ull * 6 * 4);
    int*   ti = (int*)alloc(8192ull * 6 * 4);

    hipMemsetAsync(colsum, 0, 512 * 4, stream);
    hipMemsetAsync(colsum_emb, 0, 512 * 4, stream);

    k_conv_bf16<<<(8192 * 384 / 4 + 255) / 256, 256, 0, stream>>>(feats, fb, 8192 * 384);
    k_transpose_bf16<<<(512 * 384 + 255) / 256, 256, 0, stream>>>(fc1_w, wfc1T, 384, 512);
    k_transpose_bf16<<<(512 * 512 + 255) / 256, 256, 0, stream>>>(wh_w, whT, 512, 512);
    k_transpose_bf16<<<(512 * 512 + 255) / 256, 256, 0, stream>>>(wt_w, wtT, 512, 512);
    k_transpose_bf16<<<(512 * 512 + 255) / 256, 256, 0, stream>>>(l1_w, l1T, 512, 512);
    k_transpose_bf16<<<(512 * 512 + 255) / 256, 256, 0, stream>>>(l2_w, l2T, 512, 512);

    // x0 = lrelu(feats@fc1 + b), colsum(x0)
    k_gemm<1, 1><<<dim3(64, 4, 1), 256, 0, stream>>>(
        fb, fb, wfc1T, wfc1T, fc1_b, fc1_b, xb, xb, colsum, 8192, 512, 384);
    // x = 0.5*(x0 + colmean)
    k_update_x<<<2048, 256, 0, stream>>>(xb, colsum);
    // e_h and e_t in one dual launch (z selects job)
    k_gemm<0, 0><<<dim3(64, 4, 2), 256, 0, stream>>>(
        xb, xb, whT, wtT, wh_b, wt_b, ehb, etb, nullptr, 8192, 512, 512);
    // attn logits + fused partial top-6 (16 col-splits), then merge+decode
    k_attn_topk<<<dim3(64, 16), 256, 0, stream>>>(ehb, etb, pk);
    k_merge_topk<<<32, 256, 0, stream>>>(pk, tw, ti);
    // neighbor aggregation -> s = e_h + e_Nh, p = e_h * e_Nh (bf16)
    k_agg<<<2048, 256, 0, stream>>>(ehb, etb, tw, ti, sb, pb);
    // emb colsums in one dual launch (never materialize emb)
    k_gemm<1, 2><<<dim3(64, 4, 2), 256, 0, stream>>>(
        sb, pb, l1T, l2T, l1_b, l2_b, nullptr, nullptr, colsum_emb, 8192, 512, 512);
    // mean -> LN -> classifier
    k_final<<<1, 512, 0, stream>>>(colsum_emb, ln_g, ln_b, cls_w, cls_b, (float*)d_out);
}

// Round 8
// 194.027 us; speedup vs baseline: 2.3696x; 1.0083x over previous
//
#include <hip/hip_runtime.h>
#include <math.h>

#define DEV __device__ __forceinline__

// ---- MFMA fragment types (gfx950 16x16x32 bf16) ----
using frag_ab = __attribute__((ext_vector_type(8))) short;  // 8 bf16 (4 VGPRs)
using frag_cd = __attribute__((ext_vector_type(4))) float;  // 4 fp32

static constexpr float SCALE_C = 0.04419417382415922f;  // 512^-0.5

// ---- bf16 helpers (RNE) ----
DEV unsigned short f2bf(float f) {
    unsigned u = __float_as_uint(f);
    unsigned r = (u + 0x7FFFu + ((u >> 16) & 1u)) >> 16;
    return (unsigned short)r;
}
DEV float bf2f(unsigned short h) { return __uint_as_float(((unsigned)h) << 16); }

DEV void unpack8(uint4 q, float f[8]) {
    f[0] = bf2f((unsigned short)(q.x & 0xFFFFu)); f[1] = bf2f((unsigned short)(q.x >> 16));
    f[2] = bf2f((unsigned short)(q.y & 0xFFFFu)); f[3] = bf2f((unsigned short)(q.y >> 16));
    f[4] = bf2f((unsigned short)(q.z & 0xFFFFu)); f[5] = bf2f((unsigned short)(q.z >> 16));
    f[6] = bf2f((unsigned short)(q.w & 0xFFFFu)); f[7] = bf2f((unsigned short)(q.w >> 16));
}
DEV uint4 pack8(const float f[8]) {
    uint4 q;
    q.x = (unsigned)f2bf(f[0]) | ((unsigned)f2bf(f[1]) << 16);
    q.y = (unsigned)f2bf(f[2]) | ((unsigned)f2bf(f[3]) << 16);
    q.z = (unsigned)f2bf(f[4]) | ((unsigned)f2bf(f[5]) << 16);
    q.w = (unsigned)f2bf(f[6]) | ((unsigned)f2bf(f[7]) << 16);
    return q;
}

// ---- order-preserving float<->u32 (monotone key) ----
DEV unsigned mono(float f) {
    unsigned u = __float_as_uint(f);
    return u ^ ((unsigned)((int)u >> 31) | 0x80000000u);
}
DEV float unmono(unsigned k) {
    unsigned u = (k & 0x80000000u) ? (k & 0x7FFFFFFFu) : ~k;
    return __uint_as_float(u);
}

// ---- async global->LDS 16B (direct-to-LDS DMA; dest = wave base + lane*16) ----
DEV void gload_lds16(const void* g, void* l) {
    __builtin_amdgcn_global_load_lds(
        (const __attribute__((address_space(1))) void*)g,
        (__attribute__((address_space(3))) void*)l, 16, 0, 0);
}

// ---- fused prep: z=0..4 weight transposes ([K][512]f32 -> [512][K]bf16), z=5 feats conv ----
__global__ void k_prep(const float* __restrict__ feats, const float* __restrict__ fc1_w,
                       const float* __restrict__ wh_w, const float* __restrict__ wt_w,
                       const float* __restrict__ l1_w, const float* __restrict__ l2_w,
                       unsigned short* __restrict__ fb, unsigned short* __restrict__ wfc1T,
                       unsigned short* __restrict__ whT, unsigned short* __restrict__ wtT,
                       unsigned short* __restrict__ l1T, unsigned short* __restrict__ l2T) {
    const int z = blockIdx.z;
    if (z == 5) {  // conv feats f32 -> bf16, grid-stride
        for (int i = (blockIdx.x * 256 + threadIdx.x) * 4; i < 8192 * 384; i += 1024 * 256 * 4) {
            float4 v = *(const float4*)(feats + i);
            ushort4 o;
            o.x = f2bf(v.x); o.y = f2bf(v.y); o.z = f2bf(v.z); o.w = f2bf(v.w);
            *(ushort4*)(fb + i) = o;
        }
        return;
    }
    const float* s = z == 0 ? fc1_w : z == 1 ? wh_w : z == 2 ? wt_w : z == 3 ? l1_w : l2_w;
    unsigned short* d = z == 0 ? wfc1T : z == 1 ? whT : z == 2 ? wtT : z == 3 ? l1T : l2T;
    const int K = z == 0 ? 384 : 512;
    int i = blockIdx.x * 256 + threadIdx.x;
    if (i >= K * 512) return;
    int n = i / K, k = i - n * K;
    d[i] = f2bf(s[k * 512 + n]);
}

// ---- staging (XOR-swizzled source, linear LDS dest; rule 21) ----
// 256-thread variant: 128 rows x 64 bf16 (16KB)
DEV void stage_async(const unsigned short* __restrict__ g, int ld, int k0, char* lds, int t) {
    const int sub = t >> 3;
    const int b = (t & 7) << 4;
    const int bs = b ^ ((sub & 7) << 4);
    const char* gb = (const char*)(g + k0) + (size_t)sub * (size_t)(ld * 2) + bs;
    char* lb = lds + ((t >> 6) << 10);
    const size_t rstep = (size_t)32 * (ld * 2);
#pragma unroll
    for (int r = 0; r < 4; ++r)
        gload_lds16(gb + r * rstep, lb + r * 4096);
}
// 512-thread variants: A = 256 rows (32KB), B = 128 rows (16KB); 64 rows/pass
DEV void stageA512(const unsigned short* __restrict__ g, int ld, int k0, char* lds, int t) {
    const int sub = t >> 3;  // 0..63
    const int b = (t & 7) << 4;
    const int bs = b ^ ((sub & 7) << 4);
    const char* gb = (const char*)(g + k0) + (size_t)sub * (size_t)(ld * 2) + bs;
    char* lb = lds + ((t >> 6) << 10);
    const size_t rstep = (size_t)64 * (ld * 2);
#pragma unroll
    for (int r = 0; r < 4; ++r)
        gload_lds16(gb + r * rstep, lb + r * 8192);
}
DEV void stageB512(const unsigned short* __restrict__ g, int ld, int k0, char* lds, int t) {
    const int sub = t >> 3;
    const int b = (t & 7) << 4;
    const int bs = b ^ ((sub & 7) << 4);
    const char* gb = (const char*)(g + k0) + (size_t)sub * (size_t)(ld * 2) + bs;
    char* lb = lds + ((t >> 6) << 10);
    const size_t rstep = (size_t)64 * (ld * 2);
#pragma unroll
    for (int r = 0; r < 2; ++r)
        gload_lds16(gb + r * rstep, lb + r * 8192);
}

// ---- one MxNx64 MFMA step; wave computes 64x64 at (wr,wc) ----
DEV void mfma_tile(const char* As, const char* Bs, int lane, int wr, int wc, frag_cd (&acc)[4][4]) {
#pragma unroll
    for (int ks = 0; ks < 2; ++ks) {
        const int boff = ks * 64 + ((lane >> 4) << 4);
        frag_ab av[4];
#pragma unroll
        for (int f = 0; f < 4; ++f) {
            int ra = wr * 64 + f * 16 + (lane & 15);
            av[f] = *(const frag_ab*)(As + ra * 128 + (boff ^ ((ra & 7) << 4)));
        }
#pragma unroll
        for (int j = 0; j < 4; ++j) {
            int rb = wc * 64 + j * 16 + (lane & 15);
            frag_ab bv = *(const frag_ab*)(Bs + rb * 128 + (boff ^ ((rb & 7) << 4)));
#pragma unroll
            for (int i = 0; i < 4; ++i)
                acc[i][j] = __builtin_amdgcn_mfma_f32_16x16x32_bf16(av[i], bv, acc[i][j], 0, 0, 0);
        }
    }
}

// ---- generic bf16 GEMM, 2-stage software pipeline (static buffers, unroll 1);
// blockIdx.z selects job. C = act(A @ BT^T + bias); EPI: 0=store, 1=store+colsum, 2=colsum only ----
template <int ACT, int EPI>
__global__ __launch_bounds__(256, 2) void k_gemm(
    const unsigned short* __restrict__ A0, const unsigned short* __restrict__ A1,
    const unsigned short* __restrict__ B0, const unsigned short* __restrict__ B1,
    const float* __restrict__ bias0, const float* __restrict__ bias1,
    unsigned short* __restrict__ out0, unsigned short* __restrict__ out1,
    float* __restrict__ colsum, int M, int N, int K) {
    __shared__ __align__(16) char smem[65536];
    __shared__ float colacc[128];
    char* sA0 = smem;
    char* sA1 = smem + 16384;
    char* sB0 = smem + 32768;
    char* sB1 = smem + 49152;
    const int z = blockIdx.z;
    const unsigned short* A = z ? A1 : A0;
    const unsigned short* BT = z ? B1 : B0;
    const float* bias = z ? bias1 : bias0;
    unsigned short* out = z ? out1 : out0;
    const int t = threadIdx.x;
    const int lane = t & 63, wid = t >> 6, wr = wid >> 1, wc = wid & 1;
    const int m0 = blockIdx.x * 128, n0 = blockIdx.y * 128;
    if (EPI >= 1 && t < 128) colacc[t] = 0.f;
    const unsigned short* Ap = A + (size_t)m0 * K;
    const unsigned short* Bp = BT + (size_t)n0 * K;
    frag_cd acc[4][4] = {};
    const int nt = K >> 6;  // even, >= 4
    stage_async(Ap, K, 0, sA0, t);
    stage_async(Bp, K, 0, sB0, t);
    __syncthreads();
#pragma unroll 1
    for (int tt = 0; tt < nt - 2; tt += 2) {
        stage_async(Ap, K, (tt + 1) * 64, sA1, t);
        stage_async(Bp, K, (tt + 1) * 64, sB1, t);
        mfma_tile(sA0, sB0, lane, wr, wc, acc);
        __syncthreads();
        stage_async(Ap, K, (tt + 2) * 64, sA0, t);
        stage_async(Bp, K, (tt + 2) * 64, sB0, t);
        mfma_tile(sA1, sB1, lane, wr, wc, acc);
        __syncthreads();
    }
    stage_async(Ap, K, (nt - 1) * 64, sA1, t);
    stage_async(Bp, K, (nt - 1) * 64, sB1, t);
    mfma_tile(sA0, sB0, lane, wr, wc, acc);
    __syncthreads();
    mfma_tile(sA1, sB1, lane, wr, wc, acc);
    // epilogue
    float bval[4];
#pragma unroll
    for (int j = 0; j < 4; ++j) bval[j] = bias[n0 + wc * 64 + j * 16 + (lane & 15)];
#pragma unroll
    for (int i = 0; i < 4; ++i) {
#pragma unroll
        for (int j = 0; j < 4; ++j) {
            float cs = 0.f;
#pragma unroll
            for (int r = 0; r < 4; ++r) {
                float v = acc[i][j][r] + bval[j];
                if (ACT) v = v > 0.f ? v : 0.01f * v;
                if (EPI != 2) {
                    int row = m0 + wr * 64 + i * 16 + (lane >> 4) * 4 + r;
                    int col = n0 + wc * 64 + j * 16 + (lane & 15);
                    out[(size_t)row * N + col] = f2bf(v);
                }
                cs += v;
            }
            if (EPI >= 1) atomicAdd(&colacc[wc * 64 + j * 16 + (lane & 15)], cs);
        }
    }
    if (EPI >= 1) {
        __syncthreads();
        if (t < 128) atomicAdd(&colsum[n0 + t], colacc[t]);
    }
}

// ---- x = 0.5*(x + colmean) in-place on bf16 ----
__global__ void k_update_x(unsigned short* __restrict__ xb, const float* __restrict__ colsum) {
    int i = (blockIdx.x * 256 + threadIdx.x) * 8;
    uint4 q = *(const uint4*)(xb + i);
    float f[8]; unpack8(q, f);
    int c0 = i & 511;
#pragma unroll
    for (int j = 0; j < 8; ++j) f[j] = 0.5f * (f[j] + colsum[c0 + j] * (1.f / 8192.f));
    *(uint4*)(xb + i) = pack8(f);
}

// ---- sorted-desc top-6 key list: insert via min/max chain (11 ops, dep depth 2) ----
DEV void kins(unsigned (&v)[6], unsigned k) {
    unsigned m1 = v[0] < k ? v[0] : k;
    unsigned m2 = v[1] < k ? v[1] : k;
    unsigned m3 = v[2] < k ? v[2] : k;
    unsigned m4 = v[3] < k ? v[3] : k;
    unsigned m5 = v[4] < k ? v[4] : k;
    v[0] = v[0] > k ? v[0] : k;
    v[1] = v[1] > m1 ? v[1] : m1;
    v[2] = v[2] > m2 ? v[2] : m2;
    v[3] = v[3] > m3 ? v[3] : m3;
    v[4] = v[4] > m4 ? v[4] : m4;
    v[5] = v[5] > m5 ? v[5] : m5;
}

// ---- fused attn-logit GEMM + partial top-6 (key-based), 256x128 tile, 2-stage ----
// grid (32 row-blocks, 16 col-splits); each block: 256 rows x 512 cols, 512 thr.
// LDS 96KB: sA0|sA1|sB0|sB1; key spill tile (256x68 u32 = 69.6KB) unions the
// dead buffer space during the scan phase (barrier-separated).
__global__ __launch_bounds__(512, 1) void k_attn_topk(
    const unsigned short* __restrict__ ehb, const unsigned short* __restrict__ etb,
    unsigned* __restrict__ pk) {
    __shared__ __align__(16) char smem[98304];
    char* sA0 = smem;
    char* sA1 = smem + 32768;
    char* sB0 = smem + 65536;
    char* sB1 = smem + 81920;
    unsigned* Stile = (unsigned*)smem;  // 256 x 68 u32 keys, dead during GEMM
    const int t = threadIdx.x;
    const int lane = t & 63, wid = t >> 6, wr = wid >> 1, wc = wid & 1;  // 4x2 waves
    const int m0 = blockIdx.x * 256;
    const int csplit = blockIdx.y;
    const int srow = t >> 1, hh = t & 1;  // srow 0..255
    const unsigned short* Ap = ehb + (size_t)m0 * 512;
    unsigned ka[6] = {0, 0, 0, 0, 0, 0};  // key 0 < any real key
    unsigned kb[6] = {0, 0, 0, 0, 0, 0};

    for (int ct = 0; ct < 4; ++ct) {
        const int n0 = csplit * 512 + ct * 128;
        const unsigned short* Bp = etb + (size_t)n0 * 512;
        frag_cd acc[4][4] = {};
        __syncthreads();  // prior ct's Stile scan complete before restaging
        stageA512(Ap, 512, 0, sA0, t);
        stageB512(Bp, 512, 0, sB0, t);
        __syncthreads();
#pragma unroll 1
        for (int p = 0; p < 3; ++p) {
            stageA512(Ap, 512, (2 * p + 1) * 64, sA1, t);
            stageB512(Bp, 512, (2 * p + 1) * 64, sB1, t);
            mfma_tile(sA0, sB0, lane, wr, wc, acc);
            __syncthreads();
            stageA512(Ap, 512, (2 * p + 2) * 64, sA0, t);
            stageB512(Bp, 512, (2 * p + 2) * 64, sB0, t);
            mfma_tile(sA1, sB1, lane, wr, wc, acc);
            __syncthreads();
        }
        stageA512(Ap, 512, 7 * 64, sA1, t);
        stageB512(Bp, 512, 7 * 64, sB1, t);
        mfma_tile(sA0, sB0, lane, wr, wc, acc);
        __syncthreads();
        mfma_tile(sA1, sB1, lane, wr, wc, acc);
        __syncthreads();  // all mfma reads done before key spill overwrites buffers
        // spill keys in two 64-col chunks (waves with wc==ch write), scan top-6
#pragma unroll
        for (int ch = 0; ch < 2; ++ch) {
            if (wc == ch) {
                const unsigned ckb = 8191u - (unsigned)(n0 + ch * 64 + (lane & 15));
#pragma unroll
                for (int i = 0; i < 4; ++i)
#pragma unroll
                    for (int j = 0; j < 4; ++j)
#pragma unroll
                        for (int r = 0; r < 4; ++r) {
                            int row = wr * 64 + i * 16 + (lane >> 4) * 4 + r;
                            int col = j * 16 + (lane & 15);
                            unsigned key = (mono(acc[i][j][r]) & 0xFFFFE000u) | (ckb - j * 16);
                            Stile[row * 68 + col] = key;
                        }
            }
            __syncthreads();
            // dual-list branchless scan: 8x uint4 loads, 32 min/max-chain inserts
            const uint4* srowp = (const uint4*)(Stile + srow * 68 + hh * 32);
#pragma unroll
            for (int q = 0; q < 8; ++q) {
                uint4 u = srowp[q];
                kins(ka, u.x); kins(kb, u.y);
                kins(ka, u.z); kins(kb, u.w);
            }
            __syncthreads();  // scan done before next chunk's spill
        }
    }
    // merge dual lists (kb into ka)
#pragma unroll
    for (int j = 0; j < 6; ++j) kins(ka, kb[j]);
    // merge the two half-row scanners via lane-pair shuffle (lanes 2k <-> 2k+1)
#pragma unroll
    for (int j = 0; j < 6; ++j) {
        unsigned ok = (unsigned)__shfl_xor((int)ka[j], 1, 64);
        if (hh == 0) kins(ka, ok);
    }
    if (hh == 0) {
        size_t o = ((size_t)(m0 + srow) * 16 + csplit) * 6;
#pragma unroll
        for (int j = 0; j < 6; ++j) pk[o + j] = ka[j];
    }
}

// ---- merge 16 partial top-6 key lists -> final top-6 per row; decode ----
__global__ void k_merge_topk(const unsigned* __restrict__ pk,
                             float* __restrict__ tw, int* __restrict__ ti) {
    int r = blockIdx.x * 256 + threadIdx.x;
    if (r >= 8192) return;
    unsigned v[6] = {0, 0, 0, 0, 0, 0};
    for (int s2 = 0; s2 < 16; ++s2) {
        const unsigned* p = pk + ((size_t)r * 16 + s2) * 6;
#pragma unroll
        for (int j = 0; j < 6; ++j) kins(v, p[j]);
    }
#pragma unroll
    for (int j = 0; j < 6; ++j) {
        tw[r * 6 + j] = unmono(v[j] & 0xFFFFE000u) * SCALE_C;
        ti[r * 6 + j] = 8191 - (int)(v[j] & 8191u);
    }
}

// ---- per-node neighbor aggregation: one wave per node ----
__global__ __launch_bounds__(256) void k_agg(
    const unsigned short* __restrict__ ehb, const unsigned short* __restrict__ etb,
    const float* __restrict__ tw, const int* __restrict__ ti,
    unsigned short* __restrict__ sb, unsigned short* __restrict__ pb) {
    const int t = threadIdx.x, lane = t & 63, wid = t >> 6;
    const int node = blockIdx.x * 4 + wid;
    const int d0 = lane * 8;
    float w[6]; int idx[6];
#pragma unroll
    for (int k = 0; k < 6; ++k) { w[k] = tw[node * 6 + k]; idx[k] = ti[node * 6 + k]; }
    float mx = w[0];
#pragma unroll
    for (int k = 1; k < 6; ++k) mx = fmaxf(mx, w[k]);
    float pr[6], s = 0.f;
#pragma unroll
    for (int k = 0; k < 6; ++k) { pr[k] = expf(w[k] - mx); s += pr[k]; }
    float inv = 1.f / s;
#pragma unroll
    for (int k = 0; k < 6; ++k) pr[k] *= inv;

    float eh[8]; unpack8(*(const uint4*)(ehb + (size_t)node * 512 + d0), eh);
    float nb[6][8];
#pragma unroll
    for (int k = 0; k < 6; ++k) unpack8(*(const uint4*)(etb + (size_t)idx[k] * 512 + d0), nb[k]);

    float kw[6] = {};
#pragma unroll
    for (int k = 0; k < 6; ++k) {
        float pk2 = pr[k];
#pragma unroll
        for (int j = 0; j < 8; ++j) {
            float ehr = pk2 * nb[k][j] + (1.f - pk2) * eh[j];
            float g = tanhf(eh[j] + ehr);
            kw[k] += nb[k][j] * g;
        }
    }
#pragma unroll
    for (int k = 0; k < 6; ++k)
#pragma unroll
        for (int o = 1; o < 64; o <<= 1) kw[k] += __shfl_xor(kw[k], o, 64);
    float m2 = kw[0];
#pragma unroll
    for (int k = 1; k < 6; ++k) m2 = fmaxf(m2, kw[k]);
    float kp[6], s2 = 0.f;
#pragma unroll
    for (int k = 0; k < 6; ++k) { kp[k] = expf(kw[k] - m2); s2 += kp[k]; }
    float inv2 = 1.f / s2;
#pragma unroll
    for (int k = 0; k < 6; ++k) kp[k] *= inv2;

    float sv[8], pv[8];
#pragma unroll
    for (int j = 0; j < 8; ++j) {
        float en = 0.f;
#pragma unroll
        for (int k = 0; k < 6; ++k) en += kp[k] * nb[k][j];
        sv[j] = eh[j] + en;
        pv[j] = eh[j] * en;
    }
    *(uint4*)(sb + (size_t)node * 512 + d0) = pack8(sv);
    *(uint4*)(pb + (size_t)node * 512 + d0) = pack8(pv);
}

// ---- final: node-mean -> LN -> classifier ----
DEV float blocksum512(float v, float* red, int lane, int wid) {
#pragma unroll
    for (int o = 1; o < 64; o <<= 1) v += __shfl_xor(v, o, 64);
    __syncthreads();
    if (lane == 0) red[wid] = v;
    __syncthreads();
    float s = 0.f;
#pragma unroll
    for (int w2 = 0; w2 < 8; ++w2) s += red[w2];
    return s;
}

__global__ __launch_bounds__(512) void k_final(
    const float* __restrict__ colsum_emb, const float* __restrict__ ln_g,
    const float* __restrict__ ln_b, const float* __restrict__ cls_w,
    const float* __restrict__ cls_b, float* __restrict__ out) {
    __shared__ float red[8];
    const int t = threadIdx.x, lane = t & 63, wid = t >> 6;
    float h = colsum_emb[t] * (1.f / 8192.f);
    float mu = blocksum512(h, red, lane, wid) * (1.f / 512.f);
    float d = h - mu;
    float var = blocksum512(d * d, red, lane, wid) * (1.f / 512.f);
    float y = d * rsqrtf(var + 1e-5f) * ln_g[t] + ln_b[t];
    float s0 = blocksum512(y * cls_w[t * 2 + 0], red, lane, wid);
    float s1 = blocksum512(y * cls_w[t * 2 + 1], red, lane, wid);
    if (t == 0) { out[0] = s0 + cls_b[0]; out[1] = s1 + cls_b[1]; }
}

extern "C" void kernel_launch(void* const* d_in, const int* in_sizes, int n_in,
                              void* d_out, int out_size, void* d_ws, size_t ws_size,
                              hipStream_t stream) {
    (void)in_sizes; (void)n_in; (void)out_size; (void)ws_size;
    const float* feats = (const float*)d_in[0];
    const float* fc1_w = (const float*)d_in[1];
    const float* fc1_b = (const float*)d_in[2];
    const float* wh_w  = (const float*)d_in[3];
    const float* wh_b  = (const float*)d_in[4];
    const float* wt_w  = (const float*)d_in[5];
    const float* wt_b  = (const float*)d_in[6];
    const float* l1_w  = (const float*)d_in[7];
    const float* l1_b  = (const float*)d_in[8];
    const float* l2_w  = (const float*)d_in[9];
    const float* l2_b  = (const float*)d_in[10];
    const float* ln_g  = (const float*)d_in[11];
    const float* ln_b  = (const float*)d_in[12];
    const float* cls_w = (const float*)d_in[13];
    const float* cls_b = (const float*)d_in[14];

    char* ws = (char*)d_ws;
    size_t off = 0;
    auto alloc = [&](size_t bytes) {
        char* p = ws + off;
        off += (bytes + 255) & ~(size_t)255;
        return p;
    };
    unsigned short* fb   = (unsigned short*)alloc(8192ull * 384 * 2);
    unsigned short* xb   = (unsigned short*)alloc(8192ull * 512 * 2);
    unsigned short* ehb  = (unsigned short*)alloc(8192ull * 512 * 2);
    unsigned short* etb  = (unsigned short*)alloc(8192ull * 512 * 2);
    unsigned short* sb   = (unsigned short*)alloc(8192ull * 512 * 2);
    unsigned short* pb   = (unsigned short*)alloc(8192ull * 512 * 2);
    unsigned short* wfc1T = (unsigned short*)alloc(512ull * 384 * 2);
    unsigned short* whT  = (unsigned short*)alloc(512ull * 512 * 2);
    unsigned short* wtT  = (unsigned short*)alloc(512ull * 512 * 2);
    unsigned short* l1T  = (unsigned short*)alloc(512ull * 512 * 2);
    unsigned short* l2T  = (unsigned short*)alloc(512ull * 512 * 2);
    float* colsum     = (float*)alloc(512 * 4);
    float* colsum_emb = (float*)alloc(512 * 4);
    unsigned* pk = (unsigned*)alloc(8192ull * 16 * 6 * 4);
    float* tw = (float*)alloc(8192ull * 6 * 4);
    int*   ti = (int*)alloc(8192ull * 6 * 4);

    hipMemsetAsync(colsum, 0, 512 * 4, stream);
    hipMemsetAsync(colsum_emb, 0, 512 * 4, stream);

    // fused conv + 5 weight transposes
    k_prep<<<dim3(1024, 1, 6), 256, 0, stream>>>(
        feats, fc1_w, wh_w, wt_w, l1_w, l2_w, fb, wfc1T, whT, wtT, l1T, l2T);

    // x0 = lrelu(feats@fc1 + b), colsum(x0)
    k_gemm<1, 1><<<dim3(64, 4, 1), 256, 0, stream>>>(
        fb, fb, wfc1T, wfc1T, fc1_b, fc1_b, xb, xb, colsum, 8192, 512, 384);
    // x = 0.5*(x0 + colmean)
    k_update_x<<<2048, 256, 0, stream>>>(xb, colsum);
    // e_h and e_t in one dual launch (z selects job)
    k_gemm<0, 0><<<dim3(64, 4, 2), 256, 0, stream>>>(
        xb, xb, whT, wtT, wh_b, wt_b, ehb, etb, nullptr, 8192, 512, 512);
    // attn logits + fused partial top-6 (256x128 tiles, 16 col-splits), then merge+decode
    k_attn_topk<<<dim3(32, 16), 512, 0, stream>>>(ehb, etb, pk);
    k_merge_topk<<<32, 256, 0, stream>>>(pk, tw, ti);
    // neighbor aggregation -> s = e_h + e_Nh, p = e_h * e_Nh (bf16)
    k_agg<<<2048, 256, 0, stream>>>(ehb, etb, tw, ti, sb, pb);
    // emb colsums in one dual launch (never materialize emb)
    k_gemm<1, 2><<<dim3(64, 4, 2), 256, 0, stream>>>(
        sb, pb, l1T, l2T, l1_b, l2_b, nullptr, nullptr, colsum_emb, 8192, 512, 512);
    // mean -> LN -> classifier
    k_final<<<1, 512, 0, stream>>>(colsum_emb, ln_g, ln_b, cls_w, cls_b, (float*)d_out);
}

// Round 9
// 182.736 us; speedup vs baseline: 2.5160x; 1.0618x over previous
//
#include <hip/hip_runtime.h>
#include <math.h>

#define DEV __device__ __forceinline__

// ---- MFMA fragment types (gfx950 16x16x32 bf16) ----
using frag_ab = __attribute__((ext_vector_type(8))) short;  // 8 bf16 (4 VGPRs)
using frag_cd = __attribute__((ext_vector_type(4))) float;  // 4 fp32

static constexpr float SCALE_C = 0.04419417382415922f;  // 512^-0.5

// ---- bf16 helpers (RNE) ----
DEV unsigned short f2bf(float f) {
    unsigned u = __float_as_uint(f);
    unsigned r = (u + 0x7FFFu + ((u >> 16) & 1u)) >> 16;
    return (unsigned short)r;
}
DEV float bf2f(unsigned short h) { return __uint_as_float(((unsigned)h) << 16); }

DEV void unpack8(uint4 q, float f[8]) {
    f[0] = bf2f((unsigned short)(q.x & 0xFFFFu)); f[1] = bf2f((unsigned short)(q.x >> 16));
    f[2] = bf2f((unsigned short)(q.y & 0xFFFFu)); f[3] = bf2f((unsigned short)(q.y >> 16));
    f[4] = bf2f((unsigned short)(q.z & 0xFFFFu)); f[5] = bf2f((unsigned short)(q.z >> 16));
    f[6] = bf2f((unsigned short)(q.w & 0xFFFFu)); f[7] = bf2f((unsigned short)(q.w >> 16));
}
DEV uint4 pack8(const float f[8]) {
    uint4 q;
    q.x = (unsigned)f2bf(f[0]) | ((unsigned)f2bf(f[1]) << 16);
    q.y = (unsigned)f2bf(f[2]) | ((unsigned)f2bf(f[3]) << 16);
    q.z = (unsigned)f2bf(f[4]) | ((unsigned)f2bf(f[5]) << 16);
    q.w = (unsigned)f2bf(f[6]) | ((unsigned)f2bf(f[7]) << 16);
    return q;
}

// ---- order-preserving float<->u32 (monotone key) ----
DEV unsigned mono(float f) {
    unsigned u = __float_as_uint(f);
    return u ^ ((unsigned)((int)u >> 31) | 0x80000000u);
}
DEV float unmono(unsigned k) {
    unsigned u = (k & 0x80000000u) ? (k & 0x7FFFFFFFu) : ~k;
    return __uint_as_float(u);
}

// ---- async global->LDS 16B (direct-to-LDS DMA; dest = wave base + lane*16) ----
DEV void gload_lds16(const void* g, void* l) {
    __builtin_amdgcn_global_load_lds(
        (const __attribute__((address_space(1))) void*)g,
        (__attribute__((address_space(3))) void*)l, 16, 0, 0);
}

// ---- fused prep: z=0..4 weight transposes ([K][512]f32 -> [512][K]bf16), z=5 feats conv ----
__global__ void k_prep(const float* __restrict__ feats, const float* __restrict__ fc1_w,
                       const float* __restrict__ wh_w, const float* __restrict__ wt_w,
                       const float* __restrict__ l1_w, const float* __restrict__ l2_w,
                       unsigned short* __restrict__ fb, unsigned short* __restrict__ wfc1T,
                       unsigned short* __restrict__ whT, unsigned short* __restrict__ wtT,
                       unsigned short* __restrict__ l1T, unsigned short* __restrict__ l2T) {
    const int z = blockIdx.z;
    if (z == 5) {  // conv feats f32 -> bf16, grid-stride
        for (int i = (blockIdx.x * 256 + threadIdx.x) * 4; i < 8192 * 384; i += 1024 * 256 * 4) {
            float4 v = *(const float4*)(feats + i);
            ushort4 o;
            o.x = f2bf(v.x); o.y = f2bf(v.y); o.z = f2bf(v.z); o.w = f2bf(v.w);
            *(ushort4*)(fb + i) = o;
        }
        return;
    }
    const float* s = z == 0 ? fc1_w : z == 1 ? wh_w : z == 2 ? wt_w : z == 3 ? l1_w : l2_w;
    unsigned short* d = z == 0 ? wfc1T : z == 1 ? whT : z == 2 ? wtT : z == 3 ? l1T : l2T;
    const int K = z == 0 ? 384 : 512;
    int i = blockIdx.x * 256 + threadIdx.x;
    if (i >= K * 512) return;
    int n = i / K, k = i - n * K;
    d[i] = f2bf(s[k * 512 + n]);
}

// ---- staging: 128 rows x 64 bf16 (16KB), XOR-swizzled source, linear LDS dest ----
DEV void stage_async(const unsigned short* __restrict__ g, int ld, int k0, char* lds, int t) {
    const int sub = t >> 3;
    const int b = (t & 7) << 4;
    const int bs = b ^ ((sub & 7) << 4);
    const char* gb = (const char*)(g + k0) + (size_t)sub * (size_t)(ld * 2) + bs;
    char* lb = lds + ((t >> 6) << 10);
    const size_t rstep = (size_t)32 * (ld * 2);
#pragma unroll
    for (int r = 0; r < 4; ++r)
        gload_lds16(gb + r * rstep, lb + r * 4096);
}

// ---- one 128x128x64 MFMA step (normal orientation: D row <- A-op(As)) ----
DEV void mfma_tile(const char* As, const char* Bs, int lane, int wr, int wc, frag_cd (&acc)[4][4]) {
#pragma unroll
    for (int ks = 0; ks < 2; ++ks) {
        const int boff = ks * 64 + ((lane >> 4) << 4);
        frag_ab av[4];
#pragma unroll
        for (int f = 0; f < 4; ++f) {
            int ra = wr * 64 + f * 16 + (lane & 15);
            av[f] = *(const frag_ab*)(As + ra * 128 + (boff ^ ((ra & 7) << 4)));
        }
#pragma unroll
        for (int j = 0; j < 4; ++j) {
            int rb = wc * 64 + j * 16 + (lane & 15);
            frag_ab bv = *(const frag_ab*)(Bs + rb * 128 + (boff ^ ((rb & 7) << 4)));
#pragma unroll
            for (int i = 0; i < 4; ++i)
                acc[i][j] = __builtin_amdgcn_mfma_f32_16x16x32_bf16(av[i], bv, acc[i][j], 0, 0, 0);
        }
    }
}

// ---- swapped-operand variant: acc[i][j] = mfma(et_frag(j), eh_frag(i)) = S^T tile.
// D layout (m89-verified): row=(lane>>4)*4+r <- A-op (et col), col=lane&15 <- B-op (eh row).
// So lane holds, per i: eh row = wr*64+i*16+(lane&15); et cols j*16+(lane>>4)*4+r.
DEV void mfma_tile_swp(const char* As, const char* Bs, int lane, int wr, int wc, frag_cd (&acc)[4][4]) {
#pragma unroll
    for (int ks = 0; ks < 2; ++ks) {
        const int boff = ks * 64 + ((lane >> 4) << 4);
        frag_ab av[4];
#pragma unroll
        for (int f = 0; f < 4; ++f) {
            int ra = wr * 64 + f * 16 + (lane & 15);
            av[f] = *(const frag_ab*)(As + ra * 128 + (boff ^ ((ra & 7) << 4)));
        }
#pragma unroll
        for (int j = 0; j < 4; ++j) {
            int rb = wc * 64 + j * 16 + (lane & 15);
            frag_ab bv = *(const frag_ab*)(Bs + rb * 128 + (boff ^ ((rb & 7) << 4)));
#pragma unroll
            for (int i = 0; i < 4; ++i)
                acc[i][j] = __builtin_amdgcn_mfma_f32_16x16x32_bf16(bv, av[i], acc[i][j], 0, 0, 0);
        }
    }
}

// ---- generic bf16 GEMM, 2-stage software pipeline (static buffers, unroll 1);
// blockIdx.z selects job. C = act(A @ BT^T + bias); EPI: 0=store, 1=store+colsum, 2=colsum only ----
template <int ACT, int EPI>
__global__ __launch_bounds__(256, 2) void k_gemm(
    const unsigned short* __restrict__ A0, const unsigned short* __restrict__ A1,
    const unsigned short* __restrict__ B0, const unsigned short* __restrict__ B1,
    const float* __restrict__ bias0, const float* __restrict__ bias1,
    unsigned short* __restrict__ out0, unsigned short* __restrict__ out1,
    float* __restrict__ colsum, int M, int N, int K) {
    __shared__ __align__(16) char smem[65536];
    __shared__ float colacc[128];
    char* sA0 = smem;
    char* sA1 = smem + 16384;
    char* sB0 = smem + 32768;
    char* sB1 = smem + 49152;
    const int z = blockIdx.z;
    const unsigned short* A = z ? A1 : A0;
    const unsigned short* BT = z ? B1 : B0;
    const float* bias = z ? bias1 : bias0;
    unsigned short* out = z ? out1 : out0;
    const int t = threadIdx.x;
    const int lane = t & 63, wid = t >> 6, wr = wid >> 1, wc = wid & 1;
    const int m0 = blockIdx.x * 128, n0 = blockIdx.y * 128;
    if (EPI >= 1 && t < 128) colacc[t] = 0.f;
    const unsigned short* Ap = A + (size_t)m0 * K;
    const unsigned short* Bp = BT + (size_t)n0 * K;
    frag_cd acc[4][4] = {};
    const int nt = K >> 6;  // even, >= 4
    stage_async(Ap, K, 0, sA0, t);
    stage_async(Bp, K, 0, sB0, t);
    __syncthreads();
#pragma unroll 1
    for (int tt = 0; tt < nt - 2; tt += 2) {
        stage_async(Ap, K, (tt + 1) * 64, sA1, t);
        stage_async(Bp, K, (tt + 1) * 64, sB1, t);
        mfma_tile(sA0, sB0, lane, wr, wc, acc);
        __syncthreads();
        stage_async(Ap, K, (tt + 2) * 64, sA0, t);
        stage_async(Bp, K, (tt + 2) * 64, sB0, t);
        mfma_tile(sA1, sB1, lane, wr, wc, acc);
        __syncthreads();
    }
    stage_async(Ap, K, (nt - 1) * 64, sA1, t);
    stage_async(Bp, K, (nt - 1) * 64, sB1, t);
    mfma_tile(sA0, sB0, lane, wr, wc, acc);
    __syncthreads();
    mfma_tile(sA1, sB1, lane, wr, wc, acc);
    // epilogue
    float bval[4];
#pragma unroll
    for (int j = 0; j < 4; ++j) bval[j] = bias[n0 + wc * 64 + j * 16 + (lane & 15)];
#pragma unroll
    for (int i = 0; i < 4; ++i) {
#pragma unroll
        for (int j = 0; j < 4; ++j) {
            float cs = 0.f;
#pragma unroll
            for (int r = 0; r < 4; ++r) {
                float v = acc[i][j][r] + bval[j];
                if (ACT) v = v > 0.f ? v : 0.01f * v;
                if (EPI != 2) {
                    int row = m0 + wr * 64 + i * 16 + (lane >> 4) * 4 + r;
                    int col = n0 + wc * 64 + j * 16 + (lane & 15);
                    out[(size_t)row * N + col] = f2bf(v);
                }
                cs += v;
            }
            if (EPI >= 1) atomicAdd(&colacc[wc * 64 + j * 16 + (lane & 15)], cs);
        }
    }
    if (EPI >= 1) {
        __syncthreads();
        if (t < 128) atomicAdd(&colsum[n0 + t], colacc[t]);
    }
}

// ---- x = 0.5*(x + colmean) in-place on bf16 ----
__global__ void k_update_x(unsigned short* __restrict__ xb, const float* __restrict__ colsum) {
    int i = (blockIdx.x * 256 + threadIdx.x) * 8;
    uint4 q = *(const uint4*)(xb + i);
    float f[8]; unpack8(q, f);
    int c0 = i & 511;
#pragma unroll
    for (int j = 0; j < 8; ++j) f[j] = 0.5f * (f[j] + colsum[c0 + j] * (1.f / 8192.f));
    *(uint4*)(xb + i) = pack8(f);
}

// ---- sorted-desc top-6 key list: insert via min/max chain (11 ops, dep depth 2) ----
DEV void kins(unsigned (&v)[6], unsigned k) {
    unsigned m1 = v[0] < k ? v[0] : k;
    unsigned m2 = v[1] < k ? v[1] : k;
    unsigned m3 = v[2] < k ? v[2] : k;
    unsigned m4 = v[3] < k ? v[3] : k;
    unsigned m5 = v[4] < k ? v[4] : k;
    v[0] = v[0] > k ? v[0] : k;
    v[1] = v[1] > m1 ? v[1] : m1;
    v[2] = v[2] > m2 ? v[2] : m2;
    v[3] = v[3] > m3 ? v[3] : m3;
    v[4] = v[4] > m4 ? v[4] : m4;
    v[5] = v[5] > m5 ? v[5] : m5;
}

// ---- fused attn-logit GEMM + fully in-register top-6 (swapped-operand S^T) ----
// grid (64 row-blocks, 16 col-splits); block = 128 rows x 512 cols, 256 thr.
// No key spill tile: each lane scans its own acc registers (4 row-lists).
__global__ __launch_bounds__(256, 2) void k_attn_topk(
    const unsigned short* __restrict__ ehb, const unsigned short* __restrict__ etb,
    unsigned* __restrict__ pk) {
    __shared__ __align__(16) char smem[65536];
    char* sA0 = smem;
    char* sA1 = smem + 16384;
    char* sB0 = smem + 32768;
    char* sB1 = smem + 49152;
    unsigned* xbuf = (unsigned*)smem;  // [128][6] cross-wave merge buf (3KB), used once at end
    const int t = threadIdx.x;
    const int lane = t & 63, wid = t >> 6, wr = wid >> 1, wc = wid & 1;
    const int m0 = blockIdx.x * 128;
    const int csplit = blockIdx.y;
    const unsigned short* Ap = ehb + (size_t)m0 * 512;
    unsigned kl[4][6] = {};  // per-row top-6 key lists (key 0 < any real key)

    // prologue: stage ct=0, k=0
    stage_async(Ap, 512, 0, sA0, t);
    stage_async(etb + (size_t)(csplit * 512) * 512, 512, 0, sB0, t);

#pragma unroll 1
    for (int ct = 0; ct < 4; ++ct) {
        const int n0 = csplit * 512 + ct * 128;
        const unsigned short* Bp = etb + (size_t)n0 * 512;
        frag_cd acc[4][4] = {};
        __syncthreads();  // drains prologue/tail stage of this ct
#pragma unroll 1
        for (int p = 0; p < 3; ++p) {
            stage_async(Ap, 512, (2 * p + 1) * 64, sA1, t);
            stage_async(Bp, 512, (2 * p + 1) * 64, sB1, t);
            mfma_tile_swp(sA0, sB0, lane, wr, wc, acc);
            __syncthreads();
            stage_async(Ap, 512, (2 * p + 2) * 64, sA0, t);
            stage_async(Bp, 512, (2 * p + 2) * 64, sB0, t);
            mfma_tile_swp(sA1, sB1, lane, wr, wc, acc);
            __syncthreads();
        }
        stage_async(Ap, 512, 7 * 64, sA1, t);
        stage_async(Bp, 512, 7 * 64, sB1, t);
        mfma_tile_swp(sA0, sB0, lane, wr, wc, acc);
        __syncthreads();
        if (ct < 3) {  // tail: stage next ct's k=0 into sA0/sB0 (disjoint from sA1/sB1)
            stage_async(Ap, 512, 0, sA0, t);
            stage_async(etb + (size_t)(n0 + 128) * 512, 512, 0, sB0, t);
        }
        mfma_tile_swp(sA1, sB1, lane, wr, wc, acc);
        // in-register scan of this ct's S^T tile (overlaps the tail stage's latency)
        const int base_ck = 8191 - (n0 + wc * 64 + ((lane >> 4) << 2));
#pragma unroll
        for (int i = 0; i < 4; ++i)
#pragma unroll
            for (int j = 0; j < 4; ++j)
#pragma unroll
                for (int r = 0; r < 4; ++r) {
                    unsigned key = (mono(acc[i][j][r]) & 0xFFFFE000u) |
                                   (unsigned)(base_ck - j * 16 - r);
                    kins(kl[i], key);
                }
    }
    // merge across lane>>4 groups (same eh row, disjoint et cols): xor 16 then 32
#pragma unroll
    for (int i = 0; i < 4; ++i) {
#pragma unroll
        for (int j = 0; j < 6; ++j) {
            unsigned ok = (unsigned)__shfl_xor((int)kl[i][j], 16, 64);
            kins(kl[i], ok);
        }
#pragma unroll
        for (int j = 0; j < 6; ++j) {
            unsigned ok = (unsigned)__shfl_xor((int)kl[i][j], 32, 64);
            kins(kl[i], ok);
        }
    }
    // cross-wave (wc) merge via small LDS buffer
    __syncthreads();  // all GEMM reads done; smem reusable
    if (wc == 1 && (lane >> 4) == 0) {
#pragma unroll
        for (int i = 0; i < 4; ++i) {
            int row = wr * 64 + i * 16 + lane;
#pragma unroll
            for (int j = 0; j < 6; ++j) xbuf[row * 6 + j] = kl[i][j];
        }
    }
    __syncthreads();
    if (wc == 0 && (lane >> 4) == 0) {
#pragma unroll
        for (int i = 0; i < 4; ++i) {
            int row = wr * 64 + i * 16 + lane;
#pragma unroll
            for (int j = 0; j < 6; ++j) kins(kl[i], xbuf[row * 6 + j]);
            size_t o = ((size_t)(m0 + row) * 16 + csplit) * 6;
#pragma unroll
            for (int j = 0; j < 6; ++j) pk[o + j] = kl[i][j];
        }
    }
}

// ---- merge 16 partial top-6 key lists -> final top-6 per row; decode ----
__global__ void k_merge_topk(const unsigned* __restrict__ pk,
                             float* __restrict__ tw, int* __restrict__ ti) {
    int r = blockIdx.x * 256 + threadIdx.x;
    if (r >= 8192) return;
    unsigned v[6] = {0, 0, 0, 0, 0, 0};
    for (int s2 = 0; s2 < 16; ++s2) {
        const unsigned* p = pk + ((size_t)r * 16 + s2) * 6;
#pragma unroll
        for (int j = 0; j < 6; ++j) kins(v, p[j]);
    }
#pragma unroll
    for (int j = 0; j < 6; ++j) {
        tw[r * 6 + j] = unmono(v[j] & 0xFFFFE000u) * SCALE_C;
        ti[r * 6 + j] = 8191 - (int)(v[j] & 8191u);
    }
}

// ---- per-node neighbor aggregation: one wave per node ----
__global__ __launch_bounds__(256) void k_agg(
    const unsigned short* __restrict__ ehb, const unsigned short* __restrict__ etb,
    const float* __restrict__ tw, const int* __restrict__ ti,
    unsigned short* __restrict__ sb, unsigned short* __restrict__ pb) {
    const int t = threadIdx.x, lane = t & 63, wid = t >> 6;
    const int node = blockIdx.x * 4 + wid;
    const int d0 = lane * 8;
    float w[6]; int idx[6];
#pragma unroll
    for (int k = 0; k < 6; ++k) { w[k] = tw[node * 6 + k]; idx[k] = ti[node * 6 + k]; }
    float mx = w[0];
#pragma unroll
    for (int k = 1; k < 6; ++k) mx = fmaxf(mx, w[k]);
    float pr[6], s = 0.f;
#pragma unroll
    for (int k = 0; k < 6; ++k) { pr[k] = expf(w[k] - mx); s += pr[k]; }
    float inv = 1.f / s;
#pragma unroll
    for (int k = 0; k < 6; ++k) pr[k] *= inv;

    float eh[8]; unpack8(*(const uint4*)(ehb + (size_t)node * 512 + d0), eh);
    float nb[6][8];
#pragma unroll
    for (int k = 0; k < 6; ++k) unpack8(*(const uint4*)(etb + (size_t)idx[k] * 512 + d0), nb[k]);

    float kw[6] = {};
#pragma unroll
    for (int k = 0; k < 6; ++k) {
        float pk2 = pr[k];
#pragma unroll
        for (int j = 0; j < 8; ++j) {
            float ehr = pk2 * nb[k][j] + (1.f - pk2) * eh[j];
            float g = tanhf(eh[j] + ehr);
            kw[k] += nb[k][j] * g;
        }
    }
#pragma unroll
    for (int k = 0; k < 6; ++k)
#pragma unroll
        for (int o = 1; o < 64; o <<= 1) kw[k] += __shfl_xor(kw[k], o, 64);
    float m2 = kw[0];
#pragma unroll
    for (int k = 1; k < 6; ++k) m2 = fmaxf(m2, kw[k]);
    float kp[6], s2 = 0.f;
#pragma unroll
    for (int k = 0; k < 6; ++k) { kp[k] = expf(kw[k] - m2); s2 += kp[k]; }
    float inv2 = 1.f / s2;
#pragma unroll
    for (int k = 0; k < 6; ++k) kp[k] *= inv2;

    float sv[8], pv[8];
#pragma unroll
    for (int j = 0; j < 8; ++j) {
        float en = 0.f;
#pragma unroll
        for (int k = 0; k < 6; ++k) en += kp[k] * nb[k][j];
        sv[j] = eh[j] + en;
        pv[j] = eh[j] * en;
    }
    *(uint4*)(sb + (size_t)node * 512 + d0) = pack8(sv);
    *(uint4*)(pb + (size_t)node * 512 + d0) = pack8(pv);
}

// ---- final: node-mean -> LN -> classifier ----
DEV float blocksum512(float v, float* red, int lane, int wid) {
#pragma unroll
    for (int o = 1; o < 64; o <<= 1) v += __shfl_xor(v, o, 64);
    __syncthreads();
    if (lane == 0) red[wid] = v;
    __syncthreads();
    float s = 0.f;
#pragma unroll
    for (int w2 = 0; w2 < 8; ++w2) s += red[w2];
    return s;
}

__global__ __launch_bounds__(512) void k_final(
    const float* __restrict__ colsum_emb, const float* __restrict__ ln_g,
    const float* __restrict__ ln_b, const float* __restrict__ cls_w,
    const float* __restrict__ cls_b, float* __restrict__ out) {
    __shared__ float red[8];
    const int t = threadIdx.x, lane = t & 63, wid = t >> 6;
    float h = colsum_emb[t] * (1.f / 8192.f);
    float mu = blocksum512(h, red, lane, wid) * (1.f / 512.f);
    float d = h - mu;
    float var = blocksum512(d * d, red, lane, wid) * (1.f / 512.f);
    float y = d * rsqrtf(var + 1e-5f) * ln_g[t] + ln_b[t];
    float s0 = blocksum512(y * cls_w[t * 2 + 0], red, lane, wid);
    float s1 = blocksum512(y * cls_w[t * 2 + 1], red, lane, wid);
    if (t == 0) { out[0] = s0 + cls_b[0]; out[1] = s1 + cls_b[1]; }
}

extern "C" void kernel_launch(void* const* d_in, const int* in_sizes, int n_in,
                              void* d_out, int out_size, void* d_ws, size_t ws_size,
                              hipStream_t stream) {
    (void)in_sizes; (void)n_in; (void)out_size; (void)ws_size;
    const float* feats = (const float*)d_in[0];
    const float* fc1_w = (const float*)d_in[1];
    const float* fc1_b = (const float*)d_in[2];
    const float* wh_w  = (const float*)d_in[3];
    const float* wh_b  = (const float*)d_in[4];
    const float* wt_w  = (const float*)d_in[5];
    const float* wt_b  = (const float*)d_in[6];
    const float* l1_w  = (const float*)d_in[7];
    const float* l1_b  = (const float*)d_in[8];
    const float* l2_w  = (const float*)d_in[9];
    const float* l2_b  = (const float*)d_in[10];
    const float* ln_g  = (const float*)d_in[11];
    const float* ln_b  = (const float*)d_in[12];
    const float* cls_w = (const float*)d_in[13];
    const float* cls_b = (const float*)d_in[14];

    char* ws = (char*)d_ws;
    size_t off = 0;
    auto alloc = [&](size_t bytes) {
        char* p = ws + off;
        off += (bytes + 255) & ~(size_t)255;
        return p;
    };
    unsigned short* fb   = (unsigned short*)alloc(8192ull * 384 * 2);
    unsigned short* xb   = (unsigned short*)alloc(8192ull * 512 * 2);
    unsigned short* ehb  = (unsigned short*)alloc(8192ull * 512 * 2);
    unsigned short* etb  = (unsigned short*)alloc(8192ull * 512 * 2);
    unsigned short* sb   = (unsigned short*)alloc(8192ull * 512 * 2);
    unsigned short* pb   = (unsigned short*)alloc(8192ull * 512 * 2);
    unsigned short* wfc1T = (unsigned short*)alloc(512ull * 384 * 2);
    unsigned short* whT  = (unsigned short*)alloc(512ull * 512 * 2);
    unsigned short* wtT  = (unsigned short*)alloc(512ull * 512 * 2);
    unsigned short* l1T  = (unsigned short*)alloc(512ull * 512 * 2);
    unsigned short* l2T  = (unsigned short*)alloc(512ull * 512 * 2);
    float* colsum     = (float*)alloc(512 * 4);
    float* colsum_emb = (float*)alloc(512 * 4);
    unsigned* pk = (unsigned*)alloc(8192ull * 16 * 6 * 4);
    float* tw = (float*)alloc(8192ull * 6 * 4);
    int*   ti = (int*)alloc(8192ull * 6 * 4);

    hipMemsetAsync(colsum, 0, 512 * 4, stream);
    hipMemsetAsync(colsum_emb, 0, 512 * 4, stream);

    // fused conv + 5 weight transposes
    k_prep<<<dim3(1024, 1, 6), 256, 0, stream>>>(
        feats, fc1_w, wh_w, wt_w, l1_w, l2_w, fb, wfc1T, whT, wtT, l1T, l2T);

    // x0 = lrelu(feats@fc1 + b), colsum(x0)
    k_gemm<1, 1><<<dim3(64, 4, 1), 256, 0, stream>>>(
        fb, fb, wfc1T, wfc1T, fc1_b, fc1_b, xb, xb, colsum, 8192, 512, 384);
    // x = 0.5*(x0 + colmean)
    k_update_x<<<2048, 256, 0, stream>>>(xb, colsum);
    // e_h and e_t in one dual launch (z selects job)
    k_gemm<0, 0><<<dim3(64, 4, 2), 256, 0, stream>>>(
        xb, xb, whT, wtT, wh_b, wt_b, ehb, etb, nullptr, 8192, 512, 512);
    // attn logits + fused in-register top-6 (128x128 tiles, 16 col-splits), then merge+decode
    k_attn_topk<<<dim3(64, 16), 256, 0, stream>>>(ehb, etb, pk);
    k_merge_topk<<<32, 256, 0, stream>>>(pk, tw, ti);
    // neighbor aggregation -> s = e_h + e_Nh, p = e_h * e_Nh (bf16)
    k_agg<<<2048, 256, 0, stream>>>(ehb, etb, tw, ti, sb, pb);
    // emb colsums in one dual launch (never materialize emb)
    k_gemm<1, 2><<<dim3(64, 4, 2), 256, 0, stream>>>(
        sb, pb, l1T, l2T, l1_b, l2_b, nullptr, nullptr, colsum_emb, 8192, 512, 512);
    // mean -> LN -> classifier
    k_final<<<1, 512, 0, stream>>>(colsum_emb, ln_g, ln_b, cls_w, cls_b, (float*)d_out);
}